// Round 1
// baseline (787.597 us; speedup 1.0000x reference)
//
#include <hip/hip_runtime.h>
#include <hip/hip_bf16.h>

// ---------------------------------------------------------------------------
// 2-layer GAT on MI355X.
// Pipeline per launch (all on `stream`):
//   1. CSR-by-dst build: memset counts -> hist -> scan -> scatter  (shared by both layers)
//   2. h1 = x @ W1          (fp32 tiled GEMM, K=128)
//   3. alpha_src1/alpha_dst1 per (node, head)
//   4. agg1: wave-per-node online softmax aggregation + bias + ReLU
//   5. h2 = relu_out @ W2   (same GEMM, reuses h1 buffer)
//   6. alpha2 per node (1 head, 128 ch)
//   7. agg2 -> d_out (+ b2)
// No f32 atomics anywhere; softmax computed without segment-max (scale-invariant,
// exponents bounded ~|10| so fp32 is safe).
// ---------------------------------------------------------------------------

__global__ __launch_bounds__(256) void hist_kernel(const int* __restrict__ ei,
                                                   int* __restrict__ counts, int E, int n) {
    int i = blockIdx.x * 256 + threadIdx.x;
    int tot = E + n;
    if (i >= tot) return;
    int d = (i < E) ? ei[E + i] : (i - E);   // self-loops appended at the end
    atomicAdd(&counts[d], 1);
}

// single-block scan: 256 threads, each owns a contiguous chunk; wave-shfl block scan.
__global__ __launch_bounds__(256) void scan_kernel(int* __restrict__ counts,
                                                   int* __restrict__ rowptr, int n) {
    int t = threadIdx.x;
    int chunk = (n + 255) >> 8;
    int s = t * chunk;
    int e2 = s + chunk; if (e2 > n) e2 = n;
    int sum = 0;
    for (int i = s; i < e2; ++i) sum += counts[i];
    int lane = t & 63, w = t >> 6;
    int v = sum;
    for (int off = 1; off < 64; off <<= 1) {
        int u = __shfl_up(v, off, 64);
        if (lane >= off) v += u;
    }
    __shared__ int wsum[4];
    if (lane == 63) wsum[w] = v;
    __syncthreads();
    int woff = 0;
    for (int i = 0; i < w; ++i) woff += wsum[i];
    int run = woff + v - sum;   // exclusive prefix for this thread's chunk
    for (int i = s; i < e2; ++i) {
        int c = counts[i];
        rowptr[i] = run;
        counts[i] = run;        // counts becomes the scatter cursor
        run += c;
    }
    if (t == 255) rowptr[n] = run;
}

__global__ __launch_bounds__(256) void scatter_kernel(const int* __restrict__ ei,
                                                      int* __restrict__ cursor,
                                                      int* __restrict__ srcs, int E, int n) {
    int i = blockIdx.x * 256 + threadIdx.x;
    int tot = E + n;
    if (i >= tot) return;
    int s, d;
    if (i < E) { s = ei[i]; d = ei[E + i]; } else { s = i - E; d = s; }
    int pos = atomicAdd(&cursor[d], 1);
    srcs[pos] = s;
}

// C[N,128] = A[N,128] @ B[128,128], fp32. 64x32 tile per 128-thread block.
__global__ __launch_bounds__(128) void gemm_nk128(const float* __restrict__ A,
                                                  const float* __restrict__ B,
                                                  float* __restrict__ C, int N) {
    __shared__ float As[64 * 129];                 // +1 pad: conflict-free column reads
    __shared__ __align__(16) float Bs[128 * 32];
    int row0 = blockIdx.x * 64;
    int col0 = blockIdx.y * 32;
    int t = threadIdx.x;
    for (int i = t; i < 64 * 128; i += 128) {
        int r = i >> 7, c = i & 127;
        int gr = row0 + r;
        As[r * 129 + c] = (gr < N) ? A[gr * 128 + c] : 0.f;
    }
    for (int i = t; i < 128 * 32; i += 128) {
        int r = i >> 5, c = i & 31;
        Bs[r * 32 + c] = B[r * 128 + col0 + c];
    }
    __syncthreads();
    int tx = t & 7, ty = t >> 3;        // 8 col-groups x 16 row-groups
    int rb = ty * 4, cb = tx * 4;
    float acc[4][4] = {};
#pragma unroll 8
    for (int k = 0; k < 128; ++k) {
        float4 b4 = *reinterpret_cast<const float4*>(&Bs[k * 32 + cb]);
        float a0 = As[(rb + 0) * 129 + k];
        float a1 = As[(rb + 1) * 129 + k];
        float a2 = As[(rb + 2) * 129 + k];
        float a3 = As[(rb + 3) * 129 + k];
        acc[0][0] += a0 * b4.x; acc[0][1] += a0 * b4.y; acc[0][2] += a0 * b4.z; acc[0][3] += a0 * b4.w;
        acc[1][0] += a1 * b4.x; acc[1][1] += a1 * b4.y; acc[1][2] += a1 * b4.z; acc[1][3] += a1 * b4.w;
        acc[2][0] += a2 * b4.x; acc[2][1] += a2 * b4.y; acc[2][2] += a2 * b4.z; acc[2][3] += a2 * b4.w;
        acc[3][0] += a3 * b4.x; acc[3][1] += a3 * b4.y; acc[3][2] += a3 * b4.z; acc[3][3] += a3 * b4.w;
    }
#pragma unroll
    for (int i2 = 0; i2 < 4; ++i2) {
        int gr = row0 + rb + i2;
        if (gr < N) {
            float4 o; o.x = acc[i2][0]; o.y = acc[i2][1]; o.z = acc[i2][2]; o.w = acc[i2][3];
            *reinterpret_cast<float4*>(&C[gr * 128 + col0 + cb]) = o;
        }
    }
}

// per (node, head): alpha_src/alpha_dst = dot(h[n,h,:32], att[h,:32])
__global__ __launch_bounds__(256) void alpha1_kernel(const float* __restrict__ h1,
                                                     const float* __restrict__ a_src,
                                                     const float* __restrict__ a_dst,
                                                     float* __restrict__ asrc,
                                                     float* __restrict__ adst, int n) {
    int idx = blockIdx.x * 256 + threadIdx.x;
    if (idx >= n * 4) return;
    int node = idx >> 2, h = idx & 3;
    const float* row = h1 + (size_t)node * 128 + h * 32;
    const float* as = a_src + h * 32;
    const float* ad = a_dst + h * 32;
    float s1 = 0.f, s2 = 0.f;
#pragma unroll
    for (int c = 0; c < 32; ++c) {
        float v = row[c];
        s1 += v * as[c];
        s2 += v * ad[c];
    }
    asrc[idx] = s1;
    adst[idx] = s2;
}

// per node (1 head, 128 ch): wave-per-node dot via shfl reduction
__global__ __launch_bounds__(256) void alpha2_kernel(const float* __restrict__ h2,
                                                     const float* __restrict__ a_src,
                                                     const float* __restrict__ a_dst,
                                                     float* __restrict__ asrc,
                                                     float* __restrict__ adst, int n) {
    int wid = (blockIdx.x * 256 + threadIdx.x) >> 6;
    int lane = threadIdx.x & 63;
    if (wid >= n) return;
    float v0 = h2[(size_t)wid * 128 + lane];
    float v1 = h2[(size_t)wid * 128 + 64 + lane];
    float s1 = v0 * a_src[lane] + v1 * a_src[64 + lane];
    float s2 = v0 * a_dst[lane] + v1 * a_dst[64 + lane];
    for (int off = 32; off; off >>= 1) {
        s1 += __shfl_down(s1, off, 64);
        s2 += __shfl_down(s2, off, 64);
    }
    if (lane == 0) { asrc[wid] = s1; adst[wid] = s2; }
}

// layer-1 aggregation: wave per dst node; 4 heads x 32 ch; fused bias + ReLU
__global__ __launch_bounds__(256) void agg1_kernel(const float* __restrict__ h1,
                                                   const float* __restrict__ asrc,
                                                   const float* __restrict__ adst,
                                                   const int* __restrict__ rowptr,
                                                   const int* __restrict__ srcs,
                                                   const float* __restrict__ bias,
                                                   float* __restrict__ out, int n) {
    int wid = (blockIdx.x * 256 + threadIdx.x) >> 6;
    int lane = threadIdx.x & 63;
    if (wid >= n) return;
    int d = wid;
    int beg = rowptr[d], end = rowptr[d + 1];
    float adsth = (lane < 4) ? adst[d * 4 + lane] : 0.f;
    float acc0 = 0.f, acc1 = 0.f, den = 0.f;
    for (int p = beg; p < end; ++p) {
        int s = srcs[p];
        float pv = 0.f;
        if (lane < 4) {
            float ev = asrc[s * 4 + lane] + adsth;
            ev = (ev > 0.f) ? ev : 0.2f * ev;     // leaky_relu
            pv = expf(ev);
            den += pv;
        }
        float p0 = __shfl(pv, 0, 64), p1 = __shfl(pv, 1, 64);
        float p2 = __shfl(pv, 2, 64), p3 = __shfl(pv, 3, 64);
        float w0 = (lane < 32) ? p0 : p1;   // channel lane      -> head lane>>5
        float w1 = (lane < 32) ? p2 : p3;   // channel 64+lane   -> head 2+(lane>>5)
        const float* hr = h1 + (size_t)s * 128;
        acc0 += w0 * hr[lane];
        acc1 += w1 * hr[64 + lane];
    }
    float d0 = __shfl(den, 0, 64), d1 = __shfl(den, 1, 64);
    float d2 = __shfl(den, 2, 64), d3 = __shfl(den, 3, 64);
    float dn0 = (lane < 32) ? d0 : d1;
    float dn1 = (lane < 32) ? d2 : d3;
    float* orow = out + (size_t)d * 128;
    orow[lane]      = fmaxf(bias[lane] + acc0 / dn0, 0.f);        // ReLU fused (layer-2 input)
    orow[64 + lane] = fmaxf(bias[64 + lane] + acc1 / dn1, 0.f);
}

// layer-2 aggregation: wave per dst node; 1 head x 128 ch; + b2, no ReLU
__global__ __launch_bounds__(256) void agg2_kernel(const float* __restrict__ h2,
                                                   const float* __restrict__ asrc,
                                                   const float* __restrict__ adst,
                                                   const int* __restrict__ rowptr,
                                                   const int* __restrict__ srcs,
                                                   const float* __restrict__ bias,
                                                   float* __restrict__ out, int n) {
    int wid = (blockIdx.x * 256 + threadIdx.x) >> 6;
    int lane = threadIdx.x & 63;
    if (wid >= n) return;
    int d = wid;
    int beg = rowptr[d], end = rowptr[d + 1];
    float ad = adst[d];
    float acc0 = 0.f, acc1 = 0.f, den = 0.f;
    for (int p = beg; p < end; ++p) {
        int s = srcs[p];
        float ev = asrc[s] + ad;
        ev = (ev > 0.f) ? ev : 0.2f * ev;
        float pv = expf(ev);
        den += pv;
        const float* hr = h2 + (size_t)s * 128;
        acc0 += pv * hr[lane];
        acc1 += pv * hr[64 + lane];
    }
    float* orow = out + (size_t)d * 128;
    orow[lane]      = bias[lane] + acc0 / den;
    orow[64 + lane] = bias[64 + lane] + acc1 / den;
}

extern "C" void kernel_launch(void* const* d_in, const int* in_sizes, int n_in,
                              void* d_out, int out_size, void* d_ws, size_t ws_size,
                              hipStream_t stream) {
    const float* x   = (const float*)d_in[0];
    const int*   ei  = (const int*)d_in[1];
    const float* W1  = (const float*)d_in[2];
    const float* as1 = (const float*)d_in[3];
    const float* ad1 = (const float*)d_in[4];
    const float* b1  = (const float*)d_in[5];
    const float* W2  = (const float*)d_in[6];
    const float* as2 = (const float*)d_in[7];
    const float* ad2 = (const float*)d_in[8];
    const float* b2  = (const float*)d_in[9];

    int N = in_sizes[0] / 128;
    int E = in_sizes[1] / 2;
    int tot = E + N;

    char* wsb = (char*)d_ws;
    size_t off = 0;
    auto alloc = [&](size_t bytes) {
        void* p = wsb + off;
        off += (bytes + 255) & ~(size_t)255;
        return p;
    };
    float* h1    = (float*)alloc((size_t)N * 128 * 4);   // reused as h2 after agg1
    float* out1  = (float*)alloc((size_t)N * 128 * 4);
    int*   counts= (int*)  alloc((size_t)N * 4);
    int*   rowptr= (int*)  alloc((size_t)(N + 1) * 4);
    int*   srcs  = (int*)  alloc((size_t)tot * 4);
    float* asrc1 = (float*)alloc((size_t)N * 4 * 4);
    float* adst1 = (float*)alloc((size_t)N * 4 * 4);
    float* asrc2 = (float*)alloc((size_t)N * 4);
    float* adst2 = (float*)alloc((size_t)N * 4);
    (void)ws_size; (void)n_in; (void)out_size;

    // CSR by dst (shared by both layers)
    hipMemsetAsync(counts, 0, (size_t)N * 4, stream);
    hist_kernel<<<(tot + 255) / 256, 256, 0, stream>>>(ei, counts, E, N);
    scan_kernel<<<1, 256, 0, stream>>>(counts, rowptr, N);
    scatter_kernel<<<(tot + 255) / 256, 256, 0, stream>>>(ei, counts, srcs, E, N);

    dim3 ggrid((N + 63) / 64, 4);

    // layer 1
    gemm_nk128<<<ggrid, 128, 0, stream>>>(x, W1, h1, N);
    alpha1_kernel<<<(N * 4 + 255) / 256, 256, 0, stream>>>(h1, as1, ad1, asrc1, adst1, N);
    agg1_kernel<<<(N + 3) / 4, 256, 0, stream>>>(h1, asrc1, adst1, rowptr, srcs, b1, out1, N);

    // layer 2 (h2 reuses h1 buffer)
    gemm_nk128<<<ggrid, 128, 0, stream>>>(out1, W2, h1, N);
    alpha2_kernel<<<(N + 3) / 4, 256, 0, stream>>>(h1, as2, ad2, asrc2, adst2, N);
    agg2_kernel<<<(N + 3) / 4, 256, 0, stream>>>(h1, asrc2, adst2, rowptr, srcs, b2,
                                                 (float*)d_out, N);
}

// Round 2
// 573.323 us; speedup vs baseline: 1.3737x; 1.3737x over previous
//
#include <hip/hip_runtime.h>
#include <hip/hip_bf16.h>

// ---------------------------------------------------------------------------
// 2-layer GAT on MI355X (gfx950).
//   CSR-by-dst build (hist/scan/scatter) shared by both layers.
//   GEMMs on the MFMA bf16 pipe with 2-term A-split (A_hi + A_lo, both bf16):
//     C = A_hi*B + A_lo*B  -> error dominated by B's single bf16 rounding
//     (~2e-3 abs), far inside the 1.75e-2 threshold.
//   agg1 fuses bias+ReLU and writes layer-2 input directly as bf16 hi/lo.
//   Softmax without segment-max (scale-invariant; exponents bounded ~|10|).
// ---------------------------------------------------------------------------

typedef __attribute__((ext_vector_type(8))) short bf16x8;
typedef __attribute__((ext_vector_type(4))) float f32x4;

#define LDS_STRIDE 136  // 128 + 8 pad (bf16 elems): row stride 68 dwords -> 2-way max (free)

__device__ inline unsigned short bf16bits(float v) {
    __hip_bfloat16 h = __float2bfloat16(v);
    return __builtin_bit_cast(unsigned short, h);
}
__device__ inline float bf16back(float v) {
    __hip_bfloat16 h = __float2bfloat16(v);
    return __bfloat162float(h);
}

// ---------------- CSR build ----------------

__global__ __launch_bounds__(256) void hist_kernel(const int* __restrict__ ei,
                                                   int* __restrict__ counts, int E, int n) {
    int i = blockIdx.x * 256 + threadIdx.x;
    int tot = E + n;
    if (i >= tot) return;
    int d = (i < E) ? ei[E + i] : (i - E);   // self-loops appended at the end
    atomicAdd(&counts[d], 1);
}

__global__ __launch_bounds__(256) void scan_kernel(int* __restrict__ counts,
                                                   int* __restrict__ rowptr, int n) {
    int t = threadIdx.x;
    int chunk = (n + 255) >> 8;
    int s = t * chunk;
    int e2 = s + chunk; if (e2 > n) e2 = n;
    int sum = 0;
    for (int i = s; i < e2; ++i) sum += counts[i];
    int lane = t & 63, w = t >> 6;
    int v = sum;
    for (int off = 1; off < 64; off <<= 1) {
        int u = __shfl_up(v, off, 64);
        if (lane >= off) v += u;
    }
    __shared__ int wsum[4];
    if (lane == 63) wsum[w] = v;
    __syncthreads();
    int woff = 0;
    for (int i = 0; i < w; ++i) woff += wsum[i];
    int run = woff + v - sum;   // exclusive prefix of this thread's chunk
    for (int i = s; i < e2; ++i) {
        int c = counts[i];
        rowptr[i] = run;
        counts[i] = run;        // becomes scatter cursor
        run += c;
    }
    if (t == 255) rowptr[n] = run;
}

__global__ __launch_bounds__(256) void scatter_kernel(const int* __restrict__ ei,
                                                      int* __restrict__ cursor,
                                                      int* __restrict__ srcs, int E, int n) {
    int i = blockIdx.x * 256 + threadIdx.x;
    int tot = E + n;
    if (i >= tot) return;
    int s, d;
    if (i < E) { s = ei[i]; d = ei[E + i]; } else { s = i - E; d = s; }
    int pos = atomicAdd(&cursor[d], 1);
    srcs[pos] = s;
}

// ---------------- conversions ----------------

// x [n4*4 floats] -> hi/lo bf16 split, 4 elems/thread
__global__ __launch_bounds__(256) void convsplit_kernel(const float* __restrict__ x,
                                                        unsigned short* __restrict__ hi,
                                                        unsigned short* __restrict__ lo,
                                                        int n4) {
    int i = blockIdx.x * 256 + threadIdx.x;
    if (i >= n4) return;
    float4 v = reinterpret_cast<const float4*>(x)[i];
    ushort2 h01, h23, l01, l23;
    float b;
    h01.x = bf16bits(v.x); b = bf16back(v.x); l01.x = bf16bits(v.x - b);
    h01.y = bf16bits(v.y); b = bf16back(v.y); l01.y = bf16bits(v.y - b);
    h23.x = bf16bits(v.z); b = bf16back(v.z); l23.x = bf16bits(v.z - b);
    h23.y = bf16bits(v.w); b = bf16back(v.w); l23.y = bf16bits(v.w - b);
    reinterpret_cast<ushort2*>(hi)[i * 2]     = h01;
    reinterpret_cast<ushort2*>(hi)[i * 2 + 1] = h23;
    reinterpret_cast<ushort2*>(lo)[i * 2]     = l01;
    reinterpret_cast<ushort2*>(lo)[i * 2 + 1] = l23;
}

// W [128 K][128 N] fp32 -> Bt [128 N][128 K] bf16 (transpose + round)
__global__ __launch_bounds__(256) void convWt_kernel(const float* __restrict__ W,
                                                     unsigned short* __restrict__ Bt) {
    int i = blockIdx.x * 256 + threadIdx.x;   // 16384
    int k = i >> 7, n = i & 127;
    Bt[n * 128 + k] = bf16bits(W[i]);
}

// ---------------- MFMA GEMM: C[M,128] = (Ahi+Alo)[M,128] @ B[128,128] ----------------
// Bt is B^T [n][k] bf16. 64 rows/block, 4 waves (16 rows each), full 128-col width.

__global__ __launch_bounds__(256) void gemm_mfma(const unsigned short* __restrict__ Ahi,
                                                 const unsigned short* __restrict__ Alo,
                                                 const unsigned short* __restrict__ Bt,
                                                 float* __restrict__ C, int M) {
    __shared__ unsigned short Bs[128 * LDS_STRIDE];
    int t = threadIdx.x;
    // stage B^T (32 KB) into LDS, padded row stride
    for (int i = t; i < 128 * 16; i += 256) {
        int r = i >> 4, c = (i & 15) * 8;
        uint4 v = *reinterpret_cast<const uint4*>(Bt + r * 128 + c);
        *reinterpret_cast<uint4*>(&Bs[r * LDS_STRIDE + c]) = v;
    }
    __syncthreads();

    int wave = t >> 6, lane = t & 63;
    int m16 = lane & 15, quad = lane >> 4;
    int row0 = blockIdx.x * 64 + wave * 16;
    int arow = row0 + m16;
    if (arow > M - 1) arow = M - 1;           // clamp loads; stores predicated

    f32x4 acc[8] = {};
#pragma unroll
    for (int ks = 0; ks < 4; ++ks) {
        int k0 = ks * 32 + quad * 8;
        bf16x8 a_hi = __builtin_bit_cast(bf16x8,
            *reinterpret_cast<const uint4*>(Ahi + (size_t)arow * 128 + k0));
        bf16x8 a_lo = __builtin_bit_cast(bf16x8,
            *reinterpret_cast<const uint4*>(Alo + (size_t)arow * 128 + k0));
#pragma unroll
        for (int nt = 0; nt < 8; ++nt) {
            bf16x8 b = __builtin_bit_cast(bf16x8,
                *reinterpret_cast<const uint4*>(&Bs[(nt * 16 + m16) * LDS_STRIDE + k0]));
            acc[nt] = __builtin_amdgcn_mfma_f32_16x16x32_bf16(a_lo, b, acc[nt], 0, 0, 0);
            acc[nt] = __builtin_amdgcn_mfma_f32_16x16x32_bf16(a_hi, b, acc[nt], 0, 0, 0);
        }
    }
    // C/D layout: col = lane&15, row = quad*4 + reg   [m89-verified]
#pragma unroll
    for (int nt = 0; nt < 8; ++nt) {
#pragma unroll
        for (int r = 0; r < 4; ++r) {
            int gr = row0 + quad * 4 + r;
            if (gr < M) C[(size_t)gr * 128 + nt * 16 + m16] = acc[nt][r];
        }
    }
}

// ---------------- attention coefficients ----------------

__global__ __launch_bounds__(256) void alpha1_kernel(const float* __restrict__ h1,
                                                     const float* __restrict__ a_src,
                                                     const float* __restrict__ a_dst,
                                                     float* __restrict__ asrc,
                                                     float* __restrict__ adst, int n) {
    int idx = blockIdx.x * 256 + threadIdx.x;
    if (idx >= n * 4) return;
    int node = idx >> 2, h = idx & 3;
    const float* row = h1 + (size_t)node * 128 + h * 32;
    const float* as = a_src + h * 32;
    const float* ad = a_dst + h * 32;
    float s1 = 0.f, s2 = 0.f;
#pragma unroll
    for (int c = 0; c < 32; ++c) {
        float v = row[c];
        s1 += v * as[c];
        s2 += v * ad[c];
    }
    asrc[idx] = s1;
    adst[idx] = s2;
}

__global__ __launch_bounds__(256) void alpha2_kernel(const float* __restrict__ h2,
                                                     const float* __restrict__ a_src,
                                                     const float* __restrict__ a_dst,
                                                     float* __restrict__ asrc,
                                                     float* __restrict__ adst, int n) {
    int wid = (blockIdx.x * 256 + threadIdx.x) >> 6;
    int lane = threadIdx.x & 63;
    if (wid >= n) return;
    float v0 = h2[(size_t)wid * 128 + lane];
    float v1 = h2[(size_t)wid * 128 + 64 + lane];
    float s1 = v0 * a_src[lane] + v1 * a_src[64 + lane];
    float s2 = v0 * a_dst[lane] + v1 * a_dst[64 + lane];
    for (int off = 32; off; off >>= 1) {
        s1 += __shfl_down(s1, off, 64);
        s2 += __shfl_down(s2, off, 64);
    }
    if (lane == 0) { asrc[wid] = s1; adst[wid] = s2; }
}

// ---------------- aggregation ----------------

// layer-1: wave per dst node; lane owns channels 2l,2l+1 (head = lane>>4);
// fused bias + ReLU; writes layer-2 input as bf16 hi/lo split.
__global__ __launch_bounds__(256) void agg1_kernel(const float* __restrict__ h1,
                                                   const float* __restrict__ asrc,
                                                   const float* __restrict__ adst,
                                                   const int* __restrict__ rowptr,
                                                   const int* __restrict__ srcs,
                                                   const float* __restrict__ bias,
                                                   unsigned short* __restrict__ ohi,
                                                   unsigned short* __restrict__ olo, int n) {
    int wid = (blockIdx.x * 256 + threadIdx.x) >> 6;
    int lane = threadIdx.x & 63;
    if (wid >= n) return;
    int d = wid;
    int beg = rowptr[d], end = rowptr[d + 1];
    float adsth = (lane < 4) ? adst[d * 4 + lane] : 0.f;
    int head = lane >> 4;
    float accx = 0.f, accy = 0.f, den = 0.f;
    for (int p = beg; p < end; ++p) {
        int s = srcs[p];
        float pv = 0.f;
        if (lane < 4) {
            float ev = asrc[s * 4 + lane] + adsth;
            ev = (ev > 0.f) ? ev : 0.2f * ev;     // leaky_relu
            pv = __expf(ev);
            den += pv;
        }
        float w = __shfl(pv, head, 64);
        float2 hv = *reinterpret_cast<const float2*>(h1 + (size_t)s * 128 + 2 * lane);
        accx += w * hv.x;
        accy += w * hv.y;
    }
    float dn = __shfl(den, head, 64);
    float2 bv = *reinterpret_cast<const float2*>(bias + 2 * lane);
    float v0 = fmaxf(bv.x + accx / dn, 0.f);      // ReLU fused (layer-2 input)
    float v1 = fmaxf(bv.y + accy / dn, 0.f);
    ushort2 hw, lw;
    hw.x = bf16bits(v0); lw.x = bf16bits(v0 - bf16back(v0));
    hw.y = bf16bits(v1); lw.y = bf16bits(v1 - bf16back(v1));
    reinterpret_cast<ushort2*>(ohi + (size_t)d * 128)[lane] = hw;
    reinterpret_cast<ushort2*>(olo + (size_t)d * 128)[lane] = lw;
}

// layer-2: wave per dst node; 1 head x 128 ch; + b2, no ReLU
__global__ __launch_bounds__(256) void agg2_kernel(const float* __restrict__ h2,
                                                   const float* __restrict__ asrc,
                                                   const float* __restrict__ adst,
                                                   const int* __restrict__ rowptr,
                                                   const int* __restrict__ srcs,
                                                   const float* __restrict__ bias,
                                                   float* __restrict__ out, int n) {
    int wid = (blockIdx.x * 256 + threadIdx.x) >> 6;
    int lane = threadIdx.x & 63;
    if (wid >= n) return;
    int d = wid;
    int beg = rowptr[d], end = rowptr[d + 1];
    float ad = adst[d];
    float accx = 0.f, accy = 0.f, den = 0.f;
    for (int p = beg; p < end; ++p) {
        int s = srcs[p];
        float ev = asrc[s] + ad;
        ev = (ev > 0.f) ? ev : 0.2f * ev;
        float pv = __expf(ev);
        den += pv;
        float2 hv = *reinterpret_cast<const float2*>(h2 + (size_t)s * 128 + 2 * lane);
        accx += pv * hv.x;
        accy += pv * hv.y;
    }
    float2 bv = *reinterpret_cast<const float2*>(bias + 2 * lane);
    float2 o;
    o.x = bv.x + accx / den;
    o.y = bv.y + accy / den;
    reinterpret_cast<float2*>(out + (size_t)d * 128)[lane] = o;
}

// ---------------- launch ----------------

extern "C" void kernel_launch(void* const* d_in, const int* in_sizes, int n_in,
                              void* d_out, int out_size, void* d_ws, size_t ws_size,
                              hipStream_t stream) {
    const float* x   = (const float*)d_in[0];
    const int*   ei  = (const int*)d_in[1];
    const float* W1  = (const float*)d_in[2];
    const float* as1 = (const float*)d_in[3];
    const float* ad1 = (const float*)d_in[4];
    const float* b1  = (const float*)d_in[5];
    const float* W2  = (const float*)d_in[6];
    const float* as2 = (const float*)d_in[7];
    const float* ad2 = (const float*)d_in[8];
    const float* b2  = (const float*)d_in[9];

    int N = in_sizes[0] / 128;
    int E = in_sizes[1] / 2;
    int tot = E + N;

    char* wsb = (char*)d_ws;
    size_t off = 0;
    auto alloc = [&](size_t bytes) {
        void* p = wsb + off;
        off += (bytes + 255) & ~(size_t)255;
        return p;
    };
    unsigned short* Ahi = (unsigned short*)alloc((size_t)N * 128 * 2); // x_hi; reused as out1_hi
    unsigned short* Alo = (unsigned short*)alloc((size_t)N * 128 * 2); // x_lo; reused as out1_lo
    float* h1           = (float*)alloc((size_t)N * 128 * 4);          // h1; reused as h2
    unsigned short* Bt1 = (unsigned short*)alloc(128 * 128 * 2);
    unsigned short* Bt2 = (unsigned short*)alloc(128 * 128 * 2);
    int*   counts = (int*)alloc((size_t)N * 4);
    int*   rowptr = (int*)alloc((size_t)(N + 1) * 4);
    int*   srcs   = (int*)alloc((size_t)tot * 4);
    float* asrc1  = (float*)alloc((size_t)N * 4 * 4);
    float* adst1  = (float*)alloc((size_t)N * 4 * 4);
    float* asrc2  = (float*)alloc((size_t)N * 4);
    float* adst2  = (float*)alloc((size_t)N * 4);
    (void)ws_size; (void)n_in; (void)out_size;

    // CSR by dst (shared by both layers)
    hipMemsetAsync(counts, 0, (size_t)N * 4, stream);
    hist_kernel<<<(tot + 255) / 256, 256, 0, stream>>>(ei, counts, E, N);
    scan_kernel<<<1, 256, 0, stream>>>(counts, rowptr, N);
    scatter_kernel<<<(tot + 255) / 256, 256, 0, stream>>>(ei, counts, srcs, E, N);

    // conversions
    int n4 = N * 128 / 4;
    convsplit_kernel<<<(n4 + 255) / 256, 256, 0, stream>>>(x, Ahi, Alo, n4);
    convWt_kernel<<<64, 256, 0, stream>>>(W1, Bt1);
    convWt_kernel<<<64, 256, 0, stream>>>(W2, Bt2);

    int gblocks = (N + 63) / 64;

    // layer 1
    gemm_mfma<<<gblocks, 256, 0, stream>>>(Ahi, Alo, Bt1, h1, N);
    alpha1_kernel<<<(N * 4 + 255) / 256, 256, 0, stream>>>(h1, as1, ad1, asrc1, adst1, N);
    agg1_kernel<<<(N + 3) / 4, 256, 0, stream>>>(h1, asrc1, adst1, rowptr, srcs, b1,
                                                 Ahi, Alo, N);   // out1 -> Ahi/Alo (reuse)

    // layer 2 (h2 reuses h1 buffer)
    gemm_mfma<<<gblocks, 256, 0, stream>>>(Ahi, Alo, Bt2, h1, N);
    alpha2_kernel<<<(N + 3) / 4, 256, 0, stream>>>(h1, as2, ad2, asrc2, adst2, N);
    agg2_kernel<<<(N + 3) / 4, 256, 0, stream>>>(h1, asrc2, adst2, rowptr, srcs, b2,
                                                 (float*)d_out, N);
}

// Round 3
// 477.726 us; speedup vs baseline: 1.6486x; 1.2001x over previous
//
#include <hip/hip_runtime.h>
#include <hip/hip_bf16.h>

// ---------------------------------------------------------------------------
// 2-layer GAT on MI355X (gfx950).
//   CSR-by-dst build (hist/scan/scatter) shared by both layers.
//   GEMMs on the MFMA bf16 pipe with 2-term A-split (A_hi + A_lo):
//     C = A_hi*B + A_lo*B  -> error dominated by B's single bf16 rounding.
//   h (GEMM output) is stored as packed bf16: halves the random-gather bytes
//   in the aggregation kernels (256 B/row = 2 cache lines).
//   agg loops unrolled x2 for memory-level parallelism.
//   Softmax without segment-max (scale-invariant; exponents bounded ~|10|).
// ---------------------------------------------------------------------------

typedef __attribute__((ext_vector_type(8))) short bf16x8;
typedef __attribute__((ext_vector_type(4))) float f32x4;

#define LDS_STRIDE 136  // 128 + 8 pad (bf16): row stride 68 dwords -> 2-way max (free)

__device__ inline unsigned short bf16bits(float v) {
    __hip_bfloat16 h = __float2bfloat16(v);
    return __builtin_bit_cast(unsigned short, h);
}
__device__ inline float bf16back(float v) {
    __hip_bfloat16 h = __float2bfloat16(v);
    return __bfloat162float(h);
}
// packed pair (lo 16 bits = elem0, hi = elem1) -> two fp32
__device__ inline float2 unpk(unsigned int u) {
    float2 r;
    r.x = __builtin_bit_cast(float, u << 16);
    r.y = __builtin_bit_cast(float, u & 0xffff0000u);
    return r;
}

// ---------------- CSR build ----------------

__global__ __launch_bounds__(256) void hist_kernel(const int* __restrict__ ei,
                                                   int* __restrict__ counts, int E, int n) {
    int i = blockIdx.x * 256 + threadIdx.x;
    int tot = E + n;
    if (i >= tot) return;
    int d = (i < E) ? ei[E + i] : (i - E);   // self-loops appended at the end
    atomicAdd(&counts[d], 1);
}

__global__ __launch_bounds__(256) void scan_kernel(int* __restrict__ counts,
                                                   int* __restrict__ rowptr, int n) {
    int t = threadIdx.x;
    int chunk = (n + 255) >> 8;
    int s = t * chunk;
    int e2 = s + chunk; if (e2 > n) e2 = n;
    int sum = 0;
    for (int i = s; i < e2; ++i) sum += counts[i];
    int lane = t & 63, w = t >> 6;
    int v = sum;
    for (int off = 1; off < 64; off <<= 1) {
        int u = __shfl_up(v, off, 64);
        if (lane >= off) v += u;
    }
    __shared__ int wsum[4];
    if (lane == 63) wsum[w] = v;
    __syncthreads();
    int woff = 0;
    for (int i = 0; i < w; ++i) woff += wsum[i];
    int run = woff + v - sum;   // exclusive prefix of this thread's chunk
    for (int i = s; i < e2; ++i) {
        int c = counts[i];
        rowptr[i] = run;
        counts[i] = run;        // becomes scatter cursor
        run += c;
    }
    if (t == 255) rowptr[n] = run;
}

__global__ __launch_bounds__(256) void scatter_kernel(const int* __restrict__ ei,
                                                      int* __restrict__ cursor,
                                                      int* __restrict__ srcs, int E, int n) {
    int i = blockIdx.x * 256 + threadIdx.x;
    int tot = E + n;
    if (i >= tot) return;
    int s, d;
    if (i < E) { s = ei[i]; d = ei[E + i]; } else { s = i - E; d = s; }
    int pos = atomicAdd(&cursor[d], 1);
    srcs[pos] = s;
}

// ---------------- conversions ----------------

// x -> hi/lo bf16 split, 4 elems/thread
__global__ __launch_bounds__(256) void convsplit_kernel(const float* __restrict__ x,
                                                        unsigned short* __restrict__ hi,
                                                        unsigned short* __restrict__ lo,
                                                        int n4) {
    int i = blockIdx.x * 256 + threadIdx.x;
    if (i >= n4) return;
    float4 v = reinterpret_cast<const float4*>(x)[i];
    ushort2 h01, h23, l01, l23;
    float b;
    h01.x = bf16bits(v.x); b = bf16back(v.x); l01.x = bf16bits(v.x - b);
    h01.y = bf16bits(v.y); b = bf16back(v.y); l01.y = bf16bits(v.y - b);
    h23.x = bf16bits(v.z); b = bf16back(v.z); l23.x = bf16bits(v.z - b);
    h23.y = bf16bits(v.w); b = bf16back(v.w); l23.y = bf16bits(v.w - b);
    reinterpret_cast<ushort2*>(hi)[i * 2]     = h01;
    reinterpret_cast<ushort2*>(hi)[i * 2 + 1] = h23;
    reinterpret_cast<ushort2*>(lo)[i * 2]     = l01;
    reinterpret_cast<ushort2*>(lo)[i * 2 + 1] = l23;
}

// W [128 K][128 N] fp32 -> Bt [128 N][128 K] bf16 (transpose + round)
__global__ __launch_bounds__(256) void convWt_kernel(const float* __restrict__ W,
                                                     unsigned short* __restrict__ Bt) {
    int i = blockIdx.x * 256 + threadIdx.x;   // 16384
    int k = i >> 7, n = i & 127;
    Bt[n * 128 + k] = bf16bits(W[i]);
}

// ---------------- MFMA GEMM: Hb[M,128]bf16 = (Ahi+Alo)[M,128] @ B[128,128] ----------------

__global__ __launch_bounds__(256) void gemm_mfma(const unsigned short* __restrict__ Ahi,
                                                 const unsigned short* __restrict__ Alo,
                                                 const unsigned short* __restrict__ Bt,
                                                 unsigned short* __restrict__ Hb, int M) {
    __shared__ unsigned short Bs[128 * LDS_STRIDE];
    int t = threadIdx.x;
    for (int i = t; i < 128 * 16; i += 256) {
        int r = i >> 4, c = (i & 15) * 8;
        uint4 v = *reinterpret_cast<const uint4*>(Bt + r * 128 + c);
        *reinterpret_cast<uint4*>(&Bs[r * LDS_STRIDE + c]) = v;
    }
    __syncthreads();

    int wave = t >> 6, lane = t & 63;
    int m16 = lane & 15, quad = lane >> 4;
    int row0 = blockIdx.x * 64 + wave * 16;
    int arow = row0 + m16;
    if (arow > M - 1) arow = M - 1;           // clamp loads; stores predicated

    f32x4 acc[8] = {};
#pragma unroll
    for (int ks = 0; ks < 4; ++ks) {
        int k0 = ks * 32 + quad * 8;
        bf16x8 a_hi = __builtin_bit_cast(bf16x8,
            *reinterpret_cast<const uint4*>(Ahi + (size_t)arow * 128 + k0));
        bf16x8 a_lo = __builtin_bit_cast(bf16x8,
            *reinterpret_cast<const uint4*>(Alo + (size_t)arow * 128 + k0));
#pragma unroll
        for (int nt = 0; nt < 8; ++nt) {
            bf16x8 b = __builtin_bit_cast(bf16x8,
                *reinterpret_cast<const uint4*>(&Bs[(nt * 16 + m16) * LDS_STRIDE + k0]));
            acc[nt] = __builtin_amdgcn_mfma_f32_16x16x32_bf16(a_lo, b, acc[nt], 0, 0, 0);
            acc[nt] = __builtin_amdgcn_mfma_f32_16x16x32_bf16(a_hi, b, acc[nt], 0, 0, 0);
        }
    }
    // C/D layout: col = lane&15, row = quad*4 + reg   [m89-verified]
#pragma unroll
    for (int nt = 0; nt < 8; ++nt) {
#pragma unroll
        for (int r = 0; r < 4; ++r) {
            int gr = row0 + quad * 4 + r;
            if (gr < M) Hb[(size_t)gr * 128 + nt * 16 + m16] = bf16bits(acc[nt][r]);
        }
    }
}

// ---------------- attention coefficients (bf16 h input) ----------------

__global__ __launch_bounds__(256) void alpha1_kernel(const unsigned short* __restrict__ Hb,
                                                     const float* __restrict__ a_src,
                                                     const float* __restrict__ a_dst,
                                                     float* __restrict__ asrc,
                                                     float* __restrict__ adst, int n) {
    int idx = blockIdx.x * 256 + threadIdx.x;
    if (idx >= n * 4) return;
    int node = idx >> 2, h = idx & 3;
    const uint4* rp = reinterpret_cast<const uint4*>(Hb + (size_t)node * 128 + h * 32);
    const float* as = a_src + h * 32;
    const float* ad = a_dst + h * 32;
    float s1 = 0.f, s2 = 0.f;
#pragma unroll
    for (int q = 0; q < 4; ++q) {
        uint4 v = rp[q];
        float2 f0 = unpk(v.x), f1 = unpk(v.y), f2 = unpk(v.z), f3 = unpk(v.w);
        const float* aq = as + q * 8;
        const float* dq = ad + q * 8;
        s1 += f0.x * aq[0] + f0.y * aq[1] + f1.x * aq[2] + f1.y * aq[3]
            + f2.x * aq[4] + f2.y * aq[5] + f3.x * aq[6] + f3.y * aq[7];
        s2 += f0.x * dq[0] + f0.y * dq[1] + f1.x * dq[2] + f1.y * dq[3]
            + f2.x * dq[4] + f2.y * dq[5] + f3.x * dq[6] + f3.y * dq[7];
    }
    asrc[idx] = s1;
    adst[idx] = s2;
}

__global__ __launch_bounds__(256) void alpha2_kernel(const unsigned short* __restrict__ Hb,
                                                     const float* __restrict__ a_src,
                                                     const float* __restrict__ a_dst,
                                                     float* __restrict__ asrc,
                                                     float* __restrict__ adst, int n) {
    int wid = (blockIdx.x * 256 + threadIdx.x) >> 6;
    int lane = threadIdx.x & 63;
    if (wid >= n) return;
    const unsigned int* Hw = reinterpret_cast<const unsigned int*>(Hb);
    float2 hv = unpk(Hw[(size_t)wid * 64 + lane]);
    float2 a1 = reinterpret_cast<const float2*>(a_src)[lane];
    float2 a2 = reinterpret_cast<const float2*>(a_dst)[lane];
    float s1 = hv.x * a1.x + hv.y * a1.y;
    float s2 = hv.x * a2.x + hv.y * a2.y;
    for (int off = 32; off; off >>= 1) {
        s1 += __shfl_down(s1, off, 64);
        s2 += __shfl_down(s2, off, 64);
    }
    if (lane == 0) { asrc[wid] = s1; adst[wid] = s2; }
}

// ---------------- aggregation ----------------

// layer-1: wave per dst node; lane owns ch 2l,2l+1 (head = lane>>4);
// bf16 h gather (256 B/row); x2 unroll for MLP; fused bias+ReLU;
// writes layer-2 input as bf16 hi/lo split.
__global__ __launch_bounds__(256) void agg1_kernel(const unsigned short* __restrict__ Hb,
                                                   const float* __restrict__ asrc,
                                                   const float* __restrict__ adst,
                                                   const int* __restrict__ rowptr,
                                                   const int* __restrict__ srcs,
                                                   const float* __restrict__ bias,
                                                   unsigned short* __restrict__ ohi,
                                                   unsigned short* __restrict__ olo, int n) {
    int wid = (blockIdx.x * 256 + threadIdx.x) >> 6;
    int lane = threadIdx.x & 63;
    if (wid >= n) return;
    int d = wid;
    int beg = rowptr[d], end = rowptr[d + 1];
    float adsth = (lane < 4) ? adst[d * 4 + lane] : 0.f;
    int head = lane >> 4;
    const unsigned int* Hw = reinterpret_cast<const unsigned int*>(Hb);
    float ax0 = 0.f, ay0 = 0.f, ax1 = 0.f, ay1 = 0.f, den = 0.f;
    int p = beg;
    for (; p + 1 < end; p += 2) {
        int s0 = srcs[p], s1 = srcs[p + 1];
        float pv0 = 0.f, pv1 = 0.f;
        if (lane < 4) {
            float e0 = asrc[s0 * 4 + lane] + adsth;
            e0 = (e0 > 0.f) ? e0 : 0.2f * e0;
            pv0 = __expf(e0);
            float e1 = asrc[s1 * 4 + lane] + adsth;
            e1 = (e1 > 0.f) ? e1 : 0.2f * e1;
            pv1 = __expf(e1);
            den += pv0 + pv1;
        }
        float w0 = __shfl(pv0, head, 64);
        float w1 = __shfl(pv1, head, 64);
        unsigned int u0 = Hw[(size_t)s0 * 64 + lane];
        unsigned int u1 = Hw[(size_t)s1 * 64 + lane];
        float2 h0 = unpk(u0), h1 = unpk(u1);
        ax0 += w0 * h0.x; ay0 += w0 * h0.y;
        ax1 += w1 * h1.x; ay1 += w1 * h1.y;
    }
    if (p < end) {
        int s0 = srcs[p];
        float pv0 = 0.f;
        if (lane < 4) {
            float e0 = asrc[s0 * 4 + lane] + adsth;
            e0 = (e0 > 0.f) ? e0 : 0.2f * e0;
            pv0 = __expf(e0);
            den += pv0;
        }
        float w0 = __shfl(pv0, head, 64);
        float2 h0 = unpk(Hw[(size_t)s0 * 64 + lane]);
        ax0 += w0 * h0.x; ay0 += w0 * h0.y;
    }
    float accx = ax0 + ax1, accy = ay0 + ay1;
    float dn = __shfl(den, head, 64);
    float2 bv = *reinterpret_cast<const float2*>(bias + 2 * lane);
    float v0 = fmaxf(bv.x + accx / dn, 0.f);      // ReLU fused (layer-2 input)
    float v1 = fmaxf(bv.y + accy / dn, 0.f);
    ushort2 hw, lw;
    hw.x = bf16bits(v0); lw.x = bf16bits(v0 - bf16back(v0));
    hw.y = bf16bits(v1); lw.y = bf16bits(v1 - bf16back(v1));
    reinterpret_cast<ushort2*>(ohi + (size_t)d * 128)[lane] = hw;
    reinterpret_cast<ushort2*>(olo + (size_t)d * 128)[lane] = lw;
}

// layer-2: wave per dst node; 1 head x 128 ch; bf16 h gather; + b2, no ReLU
__global__ __launch_bounds__(256) void agg2_kernel(const unsigned short* __restrict__ Hb,
                                                   const float* __restrict__ asrc,
                                                   const float* __restrict__ adst,
                                                   const int* __restrict__ rowptr,
                                                   const int* __restrict__ srcs,
                                                   const float* __restrict__ bias,
                                                   float* __restrict__ out, int n) {
    int wid = (blockIdx.x * 256 + threadIdx.x) >> 6;
    int lane = threadIdx.x & 63;
    if (wid >= n) return;
    int d = wid;
    int beg = rowptr[d], end = rowptr[d + 1];
    float ad = adst[d];
    const unsigned int* Hw = reinterpret_cast<const unsigned int*>(Hb);
    float ax0 = 0.f, ay0 = 0.f, ax1 = 0.f, ay1 = 0.f, den = 0.f;
    int p = beg;
    for (; p + 1 < end; p += 2) {
        int s0 = srcs[p], s1 = srcs[p + 1];
        float e0 = asrc[s0] + ad;
        e0 = (e0 > 0.f) ? e0 : 0.2f * e0;
        float pv0 = __expf(e0);
        float e1 = asrc[s1] + ad;
        e1 = (e1 > 0.f) ? e1 : 0.2f * e1;
        float pv1 = __expf(e1);
        den += pv0 + pv1;
        float2 h0 = unpk(Hw[(size_t)s0 * 64 + lane]);
        float2 h1 = unpk(Hw[(size_t)s1 * 64 + lane]);
        ax0 += pv0 * h0.x; ay0 += pv0 * h0.y;
        ax1 += pv1 * h1.x; ay1 += pv1 * h1.y;
    }
    if (p < end) {
        int s0 = srcs[p];
        float e0 = asrc[s0] + ad;
        e0 = (e0 > 0.f) ? e0 : 0.2f * e0;
        float pv0 = __expf(e0);
        den += pv0;
        float2 h0 = unpk(Hw[(size_t)s0 * 64 + lane]);
        ax0 += pv0 * h0.x; ay0 += pv0 * h0.y;
    }
    float2 bv = *reinterpret_cast<const float2*>(bias + 2 * lane);
    float2 o;
    o.x = bv.x + (ax0 + ax1) / den;
    o.y = bv.y + (ay0 + ay1) / den;
    reinterpret_cast<float2*>(out + (size_t)d * 128)[lane] = o;
}

// ---------------- launch ----------------

extern "C" void kernel_launch(void* const* d_in, const int* in_sizes, int n_in,
                              void* d_out, int out_size, void* d_ws, size_t ws_size,
                              hipStream_t stream) {
    const float* x   = (const float*)d_in[0];
    const int*   ei  = (const int*)d_in[1];
    const float* W1  = (const float*)d_in[2];
    const float* as1 = (const float*)d_in[3];
    const float* ad1 = (const float*)d_in[4];
    const float* b1  = (const float*)d_in[5];
    const float* W2  = (const float*)d_in[6];
    const float* as2 = (const float*)d_in[7];
    const float* ad2 = (const float*)d_in[8];
    const float* b2  = (const float*)d_in[9];

    int N = in_sizes[0] / 128;
    int E = in_sizes[1] / 2;
    int tot = E + N;

    char* wsb = (char*)d_ws;
    size_t off = 0;
    auto alloc = [&](size_t bytes) {
        void* p = wsb + off;
        off += (bytes + 255) & ~(size_t)255;
        return p;
    };
    unsigned short* Ahi = (unsigned short*)alloc((size_t)N * 128 * 2); // x_hi; reused as out1_hi
    unsigned short* Alo = (unsigned short*)alloc((size_t)N * 128 * 2); // x_lo; reused as out1_lo
    unsigned short* Hb  = (unsigned short*)alloc((size_t)N * 128 * 2); // h bf16 (h1 then h2)
    unsigned short* Bt1 = (unsigned short*)alloc(128 * 128 * 2);
    unsigned short* Bt2 = (unsigned short*)alloc(128 * 128 * 2);
    int*   counts = (int*)alloc((size_t)N * 4);
    int*   rowptr = (int*)alloc((size_t)(N + 1) * 4);
    int*   srcs   = (int*)alloc((size_t)tot * 4);
    float* asrc1  = (float*)alloc((size_t)N * 4 * 4);
    float* adst1  = (float*)alloc((size_t)N * 4 * 4);
    float* asrc2  = (float*)alloc((size_t)N * 4);
    float* adst2  = (float*)alloc((size_t)N * 4);
    (void)ws_size; (void)n_in; (void)out_size;

    // CSR by dst (shared by both layers)
    hipMemsetAsync(counts, 0, (size_t)N * 4, stream);
    hist_kernel<<<(tot + 255) / 256, 256, 0, stream>>>(ei, counts, E, N);
    scan_kernel<<<1, 256, 0, stream>>>(counts, rowptr, N);
    scatter_kernel<<<(tot + 255) / 256, 256, 0, stream>>>(ei, counts, srcs, E, N);

    // conversions
    int n4 = N * 128 / 4;
    convsplit_kernel<<<(n4 + 255) / 256, 256, 0, stream>>>(x, Ahi, Alo, n4);
    convWt_kernel<<<64, 256, 0, stream>>>(W1, Bt1);
    convWt_kernel<<<64, 256, 0, stream>>>(W2, Bt2);

    int gblocks = (N + 63) / 64;

    // layer 1
    gemm_mfma<<<gblocks, 256, 0, stream>>>(Ahi, Alo, Bt1, Hb, N);
    alpha1_kernel<<<(N * 4 + 255) / 256, 256, 0, stream>>>(Hb, as1, ad1, asrc1, adst1, N);
    agg1_kernel<<<(N + 3) / 4, 256, 0, stream>>>(Hb, asrc1, adst1, rowptr, srcs, b1,
                                                 Ahi, Alo, N);   // out1 -> Ahi/Alo (reuse)

    // layer 2
    gemm_mfma<<<gblocks, 256, 0, stream>>>(Ahi, Alo, Bt2, Hb, N);
    alpha2_kernel<<<(N + 3) / 4, 256, 0, stream>>>(Hb, as2, ad2, asrc2, adst2, N);
    agg2_kernel<<<(N + 3) / 4, 256, 0, stream>>>(Hb, asrc2, adst2, rowptr, srcs, b2,
                                                 (float*)d_out, N);
}

// Round 4
// 369.112 us; speedup vs baseline: 2.1338x; 1.2943x over previous
//
#include <hip/hip_runtime.h>
#include <hip/hip_bf16.h>

// ---------------------------------------------------------------------------
// 2-layer GAT on MI355X (gfx950).
//   CSR-by-dst build (hist / 3-stage parallel scan / scatter), shared by layers.
//   GEMMs on the MFMA bf16 pipe with 2-term A-split (A_hi + A_lo):
//     C = A_hi*B + A_lo*B  -> error dominated by B's single bf16 rounding.
//   h (GEMM output) stored as packed bf16: 256 B/row random gather.
//   agg loops unrolled x2 for memory-level parallelism.
//   Softmax without segment-max (scale-invariant; exponents bounded ~|10|).
// ---------------------------------------------------------------------------

typedef __attribute__((ext_vector_type(8))) short bf16x8;
typedef __attribute__((ext_vector_type(4))) float f32x4;

#define LDS_STRIDE 136  // 128 + 8 pad (bf16): row stride 68 dwords -> 2-way max (free)

__device__ inline unsigned short bf16bits(float v) {
    __hip_bfloat16 h = __float2bfloat16(v);
    return __builtin_bit_cast(unsigned short, h);
}
__device__ inline float bf16back(float v) {
    __hip_bfloat16 h = __float2bfloat16(v);
    return __bfloat162float(h);
}
// packed pair (lo 16 bits = elem0, hi = elem1) -> two fp32
__device__ inline float2 unpk(unsigned int u) {
    float2 r;
    r.x = __builtin_bit_cast(float, u << 16);
    r.y = __builtin_bit_cast(float, u & 0xffff0000u);
    return r;
}

// ---------------- CSR build ----------------

__global__ __launch_bounds__(256) void hist_kernel(const int* __restrict__ ei,
                                                   int* __restrict__ counts, int E, int n) {
    int i = blockIdx.x * 256 + threadIdx.x;
    int tot = E + n;
    if (i >= tot) return;
    int d = (i < E) ? ei[E + i] : (i - E);   // self-loops appended at the end
    atomicAdd(&counts[d], 1);
}

// stage 1: per-block (256-elem chunk) reduction -> bsum[b]
__global__ __launch_bounds__(256) void scan_partial(const int* __restrict__ counts,
                                                    int* __restrict__ bsum, int n) {
    int t = threadIdx.x;
    int i = blockIdx.x * 256 + t;
    int v = (i < n) ? counts[i] : 0;
    for (int off = 32; off; off >>= 1) v += __shfl_down(v, off, 64);
    __shared__ int ws[4];
    if ((t & 63) == 0) ws[t >> 6] = v;
    __syncthreads();
    if (t == 0) bsum[blockIdx.x] = ws[0] + ws[1] + ws[2] + ws[3];
}

// stage 2: single block, exclusive scan of nb (<=256) block sums in place
__global__ __launch_bounds__(256) void scan_bsums(int* __restrict__ bsum, int nb) {
    int t = threadIdx.x;
    int lane = t & 63, w = t >> 6;
    int orig = (t < nb) ? bsum[t] : 0;
    int v = orig;
    for (int off = 1; off < 64; off <<= 1) {
        int u = __shfl_up(v, off, 64);
        if (lane >= off) v += u;
    }
    __shared__ int ws[4];
    if (lane == 63) ws[w] = v;
    __syncthreads();
    int woff = 0;
    for (int i = 0; i < w; ++i) woff += ws[i];
    if (t < nb) bsum[t] = woff + v - orig;   // exclusive
}

// stage 3: in-block exclusive scan + block offset; counts becomes scatter cursor
__global__ __launch_bounds__(256) void scan_final(int* __restrict__ counts,
                                                  const int* __restrict__ bsum,
                                                  int* __restrict__ rowptr, int n, int tot) {
    int t = threadIdx.x;
    int i = blockIdx.x * 256 + t;
    int lane = t & 63, w = t >> 6;
    int orig = (i < n) ? counts[i] : 0;
    int v = orig;
    for (int off = 1; off < 64; off <<= 1) {
        int u = __shfl_up(v, off, 64);
        if (lane >= off) v += u;
    }
    __shared__ int ws[4];
    if (lane == 63) ws[w] = v;
    __syncthreads();
    int woff = 0;
    for (int k = 0; k < w; ++k) woff += ws[k];
    int excl = bsum[blockIdx.x] + woff + v - orig;
    if (i < n) {
        rowptr[i] = excl;
        counts[i] = excl;        // scatter cursor
    }
    if (blockIdx.x == 0 && t == 0) rowptr[n] = tot;
}

__global__ __launch_bounds__(256) void scatter_kernel(const int* __restrict__ ei,
                                                      int* __restrict__ cursor,
                                                      int* __restrict__ srcs, int E, int n) {
    int i = blockIdx.x * 256 + threadIdx.x;
    int tot = E + n;
    if (i >= tot) return;
    int s, d;
    if (i < E) { s = ei[i]; d = ei[E + i]; } else { s = i - E; d = s; }
    int pos = atomicAdd(&cursor[d], 1);
    srcs[pos] = s;
}

// ---------------- conversions ----------------

// x -> hi/lo bf16 split, 4 elems/thread
__global__ __launch_bounds__(256) void convsplit_kernel(const float* __restrict__ x,
                                                        unsigned short* __restrict__ hi,
                                                        unsigned short* __restrict__ lo,
                                                        int n4) {
    int i = blockIdx.x * 256 + threadIdx.x;
    if (i >= n4) return;
    float4 v = reinterpret_cast<const float4*>(x)[i];
    ushort2 h01, h23, l01, l23;
    float b;
    h01.x = bf16bits(v.x); b = bf16back(v.x); l01.x = bf16bits(v.x - b);
    h01.y = bf16bits(v.y); b = bf16back(v.y); l01.y = bf16bits(v.y - b);
    h23.x = bf16bits(v.z); b = bf16back(v.z); l23.x = bf16bits(v.z - b);
    h23.y = bf16bits(v.w); b = bf16back(v.w); l23.y = bf16bits(v.w - b);
    reinterpret_cast<ushort2*>(hi)[i * 2]     = h01;
    reinterpret_cast<ushort2*>(hi)[i * 2 + 1] = h23;
    reinterpret_cast<ushort2*>(lo)[i * 2]     = l01;
    reinterpret_cast<ushort2*>(lo)[i * 2 + 1] = l23;
}

// W [128 K][128 N] fp32 -> Bt [128 N][128 K] bf16 (transpose + round)
__global__ __launch_bounds__(256) void convWt_kernel(const float* __restrict__ W,
                                                     unsigned short* __restrict__ Bt) {
    int i = blockIdx.x * 256 + threadIdx.x;   // 16384
    int k = i >> 7, n = i & 127;
    Bt[n * 128 + k] = bf16bits(W[i]);
}

// ---------------- MFMA GEMM: Hb[M,128]bf16 = (Ahi+Alo)[M,128] @ B[128,128] ----------------

__global__ __launch_bounds__(256) void gemm_mfma(const unsigned short* __restrict__ Ahi,
                                                 const unsigned short* __restrict__ Alo,
                                                 const unsigned short* __restrict__ Bt,
                                                 unsigned short* __restrict__ Hb, int M) {
    __shared__ unsigned short Bs[128 * LDS_STRIDE];
    int t = threadIdx.x;
    for (int i = t; i < 128 * 16; i += 256) {
        int r = i >> 4, c = (i & 15) * 8;
        uint4 v = *reinterpret_cast<const uint4*>(Bt + r * 128 + c);
        *reinterpret_cast<uint4*>(&Bs[r * LDS_STRIDE + c]) = v;
    }
    __syncthreads();

    int wave = t >> 6, lane = t & 63;
    int m16 = lane & 15, quad = lane >> 4;
    int row0 = blockIdx.x * 64 + wave * 16;
    int arow = row0 + m16;
    if (arow > M - 1) arow = M - 1;           // clamp loads; stores predicated

    f32x4 acc[8] = {};
#pragma unroll
    for (int ks = 0; ks < 4; ++ks) {
        int k0 = ks * 32 + quad * 8;
        bf16x8 a_hi = __builtin_bit_cast(bf16x8,
            *reinterpret_cast<const uint4*>(Ahi + (size_t)arow * 128 + k0));
        bf16x8 a_lo = __builtin_bit_cast(bf16x8,
            *reinterpret_cast<const uint4*>(Alo + (size_t)arow * 128 + k0));
#pragma unroll
        for (int nt = 0; nt < 8; ++nt) {
            bf16x8 b = __builtin_bit_cast(bf16x8,
                *reinterpret_cast<const uint4*>(&Bs[(nt * 16 + m16) * LDS_STRIDE + k0]));
            acc[nt] = __builtin_amdgcn_mfma_f32_16x16x32_bf16(a_lo, b, acc[nt], 0, 0, 0);
            acc[nt] = __builtin_amdgcn_mfma_f32_16x16x32_bf16(a_hi, b, acc[nt], 0, 0, 0);
        }
    }
    // C/D layout: col = lane&15, row = quad*4 + reg   [m89-verified]
#pragma unroll
    for (int nt = 0; nt < 8; ++nt) {
#pragma unroll
        for (int r = 0; r < 4; ++r) {
            int gr = row0 + quad * 4 + r;
            if (gr < M) Hb[(size_t)gr * 128 + nt * 16 + m16] = bf16bits(acc[nt][r]);
        }
    }
}

// ---------------- attention coefficients (bf16 h input) ----------------

__global__ __launch_bounds__(256) void alpha1_kernel(const unsigned short* __restrict__ Hb,
                                                     const float* __restrict__ a_src,
                                                     const float* __restrict__ a_dst,
                                                     float* __restrict__ asrc,
                                                     float* __restrict__ adst, int n) {
    int idx = blockIdx.x * 256 + threadIdx.x;
    if (idx >= n * 4) return;
    int node = idx >> 2, h = idx & 3;
    const uint4* rp = reinterpret_cast<const uint4*>(Hb + (size_t)node * 128 + h * 32);
    const float* as = a_src + h * 32;
    const float* ad = a_dst + h * 32;
    float s1 = 0.f, s2 = 0.f;
#pragma unroll
    for (int q = 0; q < 4; ++q) {
        uint4 v = rp[q];
        float2 f0 = unpk(v.x), f1 = unpk(v.y), f2 = unpk(v.z), f3 = unpk(v.w);
        const float* aq = as + q * 8;
        const float* dq = ad + q * 8;
        s1 += f0.x * aq[0] + f0.y * aq[1] + f1.x * aq[2] + f1.y * aq[3]
            + f2.x * aq[4] + f2.y * aq[5] + f3.x * aq[6] + f3.y * aq[7];
        s2 += f0.x * dq[0] + f0.y * dq[1] + f1.x * dq[2] + f1.y * dq[3]
            + f2.x * dq[4] + f2.y * dq[5] + f3.x * dq[6] + f3.y * dq[7];
    }
    asrc[idx] = s1;
    adst[idx] = s2;
}

__global__ __launch_bounds__(256) void alpha2_kernel(const unsigned short* __restrict__ Hb,
                                                     const float* __restrict__ a_src,
                                                     const float* __restrict__ a_dst,
                                                     float* __restrict__ asrc,
                                                     float* __restrict__ adst, int n) {
    int wid = (blockIdx.x * 256 + threadIdx.x) >> 6;
    int lane = threadIdx.x & 63;
    if (wid >= n) return;
    const unsigned int* Hw = reinterpret_cast<const unsigned int*>(Hb);
    float2 hv = unpk(Hw[(size_t)wid * 64 + lane]);
    float2 a1 = reinterpret_cast<const float2*>(a_src)[lane];
    float2 a2 = reinterpret_cast<const float2*>(a_dst)[lane];
    float s1 = hv.x * a1.x + hv.y * a1.y;
    float s2 = hv.x * a2.x + hv.y * a2.y;
    for (int off = 32; off; off >>= 1) {
        s1 += __shfl_down(s1, off, 64);
        s2 += __shfl_down(s2, off, 64);
    }
    if (lane == 0) { asrc[wid] = s1; adst[wid] = s2; }
}

// ---------------- aggregation ----------------

// layer-1: wave per dst node; lane owns ch 2l,2l+1 (head = lane>>4);
// bf16 h gather (256 B/row); x2 unroll for MLP; fused bias+ReLU;
// writes layer-2 input as bf16 hi/lo split.
__global__ __launch_bounds__(256) void agg1_kernel(const unsigned short* __restrict__ Hb,
                                                   const float* __restrict__ asrc,
                                                   const float* __restrict__ adst,
                                                   const int* __restrict__ rowptr,
                                                   const int* __restrict__ srcs,
                                                   const float* __restrict__ bias,
                                                   unsigned short* __restrict__ ohi,
                                                   unsigned short* __restrict__ olo, int n) {
    int wid = (blockIdx.x * 256 + threadIdx.x) >> 6;
    int lane = threadIdx.x & 63;
    if (wid >= n) return;
    int d = wid;
    int beg = rowptr[d], end = rowptr[d + 1];
    float adsth = (lane < 4) ? adst[d * 4 + lane] : 0.f;
    int head = lane >> 4;
    const unsigned int* Hw = reinterpret_cast<const unsigned int*>(Hb);
    float ax0 = 0.f, ay0 = 0.f, ax1 = 0.f, ay1 = 0.f, den = 0.f;
    int p = beg;
    for (; p + 1 < end; p += 2) {
        int s0 = srcs[p], s1 = srcs[p + 1];
        float pv0 = 0.f, pv1 = 0.f;
        if (lane < 4) {
            float e0 = asrc[s0 * 4 + lane] + adsth;
            e0 = (e0 > 0.f) ? e0 : 0.2f * e0;
            pv0 = __expf(e0);
            float e1 = asrc[s1 * 4 + lane] + adsth;
            e1 = (e1 > 0.f) ? e1 : 0.2f * e1;
            pv1 = __expf(e1);
            den += pv0 + pv1;
        }
        float w0 = __shfl(pv0, head, 64);
        float w1 = __shfl(pv1, head, 64);
        unsigned int u0 = Hw[(size_t)s0 * 64 + lane];
        unsigned int u1 = Hw[(size_t)s1 * 64 + lane];
        float2 h0 = unpk(u0), h1 = unpk(u1);
        ax0 += w0 * h0.x; ay0 += w0 * h0.y;
        ax1 += w1 * h1.x; ay1 += w1 * h1.y;
    }
    if (p < end) {
        int s0 = srcs[p];
        float pv0 = 0.f;
        if (lane < 4) {
            float e0 = asrc[s0 * 4 + lane] + adsth;
            e0 = (e0 > 0.f) ? e0 : 0.2f * e0;
            pv0 = __expf(e0);
            den += pv0;
        }
        float w0 = __shfl(pv0, head, 64);
        float2 h0 = unpk(Hw[(size_t)s0 * 64 + lane]);
        ax0 += w0 * h0.x; ay0 += w0 * h0.y;
    }
    float accx = ax0 + ax1, accy = ay0 + ay1;
    float dn = __shfl(den, head, 64);
    float2 bv = *reinterpret_cast<const float2*>(bias + 2 * lane);
    float v0 = fmaxf(bv.x + accx / dn, 0.f);      // ReLU fused (layer-2 input)
    float v1 = fmaxf(bv.y + accy / dn, 0.f);
    ushort2 hw, lw;
    hw.x = bf16bits(v0); lw.x = bf16bits(v0 - bf16back(v0));
    hw.y = bf16bits(v1); lw.y = bf16bits(v1 - bf16back(v1));
    reinterpret_cast<ushort2*>(ohi + (size_t)d * 128)[lane] = hw;
    reinterpret_cast<ushort2*>(olo + (size_t)d * 128)[lane] = lw;
}

// layer-2: wave per dst node; 1 head x 128 ch; bf16 h gather; + b2, no ReLU
__global__ __launch_bounds__(256) void agg2_kernel(const unsigned short* __restrict__ Hb,
                                                   const float* __restrict__ asrc,
                                                   const float* __restrict__ adst,
                                                   const int* __restrict__ rowptr,
                                                   const int* __restrict__ srcs,
                                                   const float* __restrict__ bias,
                                                   float* __restrict__ out, int n) {
    int wid = (blockIdx.x * 256 + threadIdx.x) >> 6;
    int lane = threadIdx.x & 63;
    if (wid >= n) return;
    int d = wid;
    int beg = rowptr[d], end = rowptr[d + 1];
    float ad = adst[d];
    const unsigned int* Hw = reinterpret_cast<const unsigned int*>(Hb);
    float ax0 = 0.f, ay0 = 0.f, ax1 = 0.f, ay1 = 0.f, den = 0.f;
    int p = beg;
    for (; p + 1 < end; p += 2) {
        int s0 = srcs[p], s1 = srcs[p + 1];
        float e0 = asrc[s0] + ad;
        e0 = (e0 > 0.f) ? e0 : 0.2f * e0;
        float pv0 = __expf(e0);
        float e1 = asrc[s1] + ad;
        e1 = (e1 > 0.f) ? e1 : 0.2f * e1;
        float pv1 = __expf(e1);
        den += pv0 + pv1;
        float2 h0 = unpk(Hw[(size_t)s0 * 64 + lane]);
        float2 h1 = unpk(Hw[(size_t)s1 * 64 + lane]);
        ax0 += pv0 * h0.x; ay0 += pv0 * h0.y;
        ax1 += pv1 * h1.x; ay1 += pv1 * h1.y;
    }
    if (p < end) {
        int s0 = srcs[p];
        float e0 = asrc[s0] + ad;
        e0 = (e0 > 0.f) ? e0 : 0.2f * e0;
        float pv0 = __expf(e0);
        den += pv0;
        float2 h0 = unpk(Hw[(size_t)s0 * 64 + lane]);
        ax0 += pv0 * h0.x; ay0 += pv0 * h0.y;
    }
    float2 bv = *reinterpret_cast<const float2*>(bias + 2 * lane);
    float2 o;
    o.x = bv.x + (ax0 + ax1) / den;
    o.y = bv.y + (ay0 + ay1) / den;
    reinterpret_cast<float2*>(out + (size_t)d * 128)[lane] = o;
}

// ---------------- launch ----------------

extern "C" void kernel_launch(void* const* d_in, const int* in_sizes, int n_in,
                              void* d_out, int out_size, void* d_ws, size_t ws_size,
                              hipStream_t stream) {
    const float* x   = (const float*)d_in[0];
    const int*   ei  = (const int*)d_in[1];
    const float* W1  = (const float*)d_in[2];
    const float* as1 = (const float*)d_in[3];
    const float* ad1 = (const float*)d_in[4];
    const float* b1  = (const float*)d_in[5];
    const float* W2  = (const float*)d_in[6];
    const float* as2 = (const float*)d_in[7];
    const float* ad2 = (const float*)d_in[8];
    const float* b2  = (const float*)d_in[9];

    int N = in_sizes[0] / 128;
    int E = in_sizes[1] / 2;
    int tot = E + N;
    int nb = (N + 255) / 256;   // scan blocks (<=256 required; N=50k -> 196)

    char* wsb = (char*)d_ws;
    size_t off = 0;
    auto alloc = [&](size_t bytes) {
        void* p = wsb + off;
        off += (bytes + 255) & ~(size_t)255;
        return p;
    };
    unsigned short* Ahi = (unsigned short*)alloc((size_t)N * 128 * 2); // x_hi; reused as out1_hi
    unsigned short* Alo = (unsigned short*)alloc((size_t)N * 128 * 2); // x_lo; reused as out1_lo
    unsigned short* Hb  = (unsigned short*)alloc((size_t)N * 128 * 2); // h bf16 (h1 then h2)
    unsigned short* Bt1 = (unsigned short*)alloc(128 * 128 * 2);
    unsigned short* Bt2 = (unsigned short*)alloc(128 * 128 * 2);
    int*   counts = (int*)alloc((size_t)N * 4);
    int*   rowptr = (int*)alloc((size_t)(N + 1) * 4);
    int*   srcs   = (int*)alloc((size_t)tot * 4);
    int*   bsum   = (int*)alloc(256 * 4);
    float* asrc1  = (float*)alloc((size_t)N * 4 * 4);
    float* adst1  = (float*)alloc((size_t)N * 4 * 4);
    float* asrc2  = (float*)alloc((size_t)N * 4);
    float* adst2  = (float*)alloc((size_t)N * 4);
    (void)ws_size; (void)n_in; (void)out_size;

    // CSR by dst (shared by both layers) — parallel 3-stage scan
    hipMemsetAsync(counts, 0, (size_t)N * 4, stream);
    hist_kernel<<<(tot + 255) / 256, 256, 0, stream>>>(ei, counts, E, N);
    scan_partial<<<nb, 256, 0, stream>>>(counts, bsum, N);
    scan_bsums<<<1, 256, 0, stream>>>(bsum, nb);
    scan_final<<<nb, 256, 0, stream>>>(counts, bsum, rowptr, N, tot);
    scatter_kernel<<<(tot + 255) / 256, 256, 0, stream>>>(ei, counts, srcs, E, N);

    // conversions
    int n4 = N * 128 / 4;
    convsplit_kernel<<<(n4 + 255) / 256, 256, 0, stream>>>(x, Ahi, Alo, n4);
    convWt_kernel<<<64, 256, 0, stream>>>(W1, Bt1);
    convWt_kernel<<<64, 256, 0, stream>>>(W2, Bt2);

    int gblocks = (N + 63) / 64;

    // layer 1
    gemm_mfma<<<gblocks, 256, 0, stream>>>(Ahi, Alo, Bt1, Hb, N);
    alpha1_kernel<<<(N * 4 + 255) / 256, 256, 0, stream>>>(Hb, as1, ad1, asrc1, adst1, N);
    agg1_kernel<<<(N + 3) / 4, 256, 0, stream>>>(Hb, asrc1, adst1, rowptr, srcs, b1,
                                                 Ahi, Alo, N);   // out1 -> Ahi/Alo (reuse)

    // layer 2
    gemm_mfma<<<gblocks, 256, 0, stream>>>(Ahi, Alo, Bt2, Hb, N);
    alpha2_kernel<<<(N + 3) / 4, 256, 0, stream>>>(Hb, as2, ad2, asrc2, adst2, N);
    agg2_kernel<<<(N + 3) / 4, 256, 0, stream>>>(Hb, asrc2, adst2, rowptr, srcs, b2,
                                                 (float*)d_out, N);
}

// Round 5
// 304.164 us; speedup vs baseline: 2.5894x; 1.2135x over previous
//
#include <hip/hip_runtime.h>
#include <hip/hip_bf16.h>

// ---------------------------------------------------------------------------
// 2-layer GAT on MI355X (gfx950).
//   CSR-by-dst build (hist / 3-stage parallel scan / scatter), shared by layers.
//   GEMMs on the MFMA bf16 pipe with 2-term A-split (A_hi + A_lo):
//     C = A_hi*B + A_lo*B  -> error dominated by B's single bf16 rounding.
//   h (GEMM output) stored as packed bf16 (256 B/row).
//   agg kernels: lane = (channel-group, edge-slot); one dwordx4 gather covers
//   4 edges; per-lane exp (no per-edge shfl); quad-reduce once per node.
//   Softmax without segment-max (scale-invariant; exponents bounded ~|10|).
// ---------------------------------------------------------------------------

typedef __attribute__((ext_vector_type(8))) short bf16x8;
typedef __attribute__((ext_vector_type(4))) float f32x4;

#define LDS_STRIDE 136  // 128 + 8 pad (bf16): row stride 68 dwords -> 2-way max (free)

__device__ inline unsigned short bf16bits(float v) {
    __hip_bfloat16 h = __float2bfloat16(v);
    return __builtin_bit_cast(unsigned short, h);
}
__device__ inline float bf16back(float v) {
    __hip_bfloat16 h = __float2bfloat16(v);
    return __bfloat162float(h);
}
// packed pair (lo 16 bits = elem0, hi = elem1) -> two fp32
__device__ inline float2 unpk(unsigned int u) {
    float2 r;
    r.x = __builtin_bit_cast(float, u << 16);
    r.y = __builtin_bit_cast(float, u & 0xffff0000u);
    return r;
}
__device__ inline unsigned int pk2(float a, float b) {
    return (unsigned int)bf16bits(a) | ((unsigned int)bf16bits(b) << 16);
}

// ---------------- CSR build ----------------

__global__ __launch_bounds__(256) void hist_kernel(const int* __restrict__ ei,
                                                   int* __restrict__ counts, int E, int n) {
    int i = blockIdx.x * 256 + threadIdx.x;
    int tot = E + n;
    if (i >= tot) return;
    int d = (i < E) ? ei[E + i] : (i - E);   // self-loops appended at the end
    atomicAdd(&counts[d], 1);
}

// stage 1: per-block (256-elem chunk) reduction -> bsum[b]
__global__ __launch_bounds__(256) void scan_partial(const int* __restrict__ counts,
                                                    int* __restrict__ bsum, int n) {
    int t = threadIdx.x;
    int i = blockIdx.x * 256 + t;
    int v = (i < n) ? counts[i] : 0;
    for (int off = 32; off; off >>= 1) v += __shfl_down(v, off, 64);
    __shared__ int ws[4];
    if ((t & 63) == 0) ws[t >> 6] = v;
    __syncthreads();
    if (t == 0) bsum[blockIdx.x] = ws[0] + ws[1] + ws[2] + ws[3];
}

// stage 2: single block, exclusive scan of nb (<=256) block sums in place
__global__ __launch_bounds__(256) void scan_bsums(int* __restrict__ bsum, int nb) {
    int t = threadIdx.x;
    int lane = t & 63, w = t >> 6;
    int orig = (t < nb) ? bsum[t] : 0;
    int v = orig;
    for (int off = 1; off < 64; off <<= 1) {
        int u = __shfl_up(v, off, 64);
        if (lane >= off) v += u;
    }
    __shared__ int ws[4];
    if (lane == 63) ws[w] = v;
    __syncthreads();
    int woff = 0;
    for (int i = 0; i < w; ++i) woff += ws[i];
    if (t < nb) bsum[t] = woff + v - orig;   // exclusive
}

// stage 3: in-block exclusive scan + block offset; counts becomes scatter cursor
__global__ __launch_bounds__(256) void scan_final(int* __restrict__ counts,
                                                  const int* __restrict__ bsum,
                                                  int* __restrict__ rowptr, int n, int tot) {
    int t = threadIdx.x;
    int i = blockIdx.x * 256 + t;
    int lane = t & 63, w = t >> 6;
    int orig = (i < n) ? counts[i] : 0;
    int v = orig;
    for (int off = 1; off < 64; off <<= 1) {
        int u = __shfl_up(v, off, 64);
        if (lane >= off) v += u;
    }
    __shared__ int ws[4];
    if (lane == 63) ws[w] = v;
    __syncthreads();
    int woff = 0;
    for (int k = 0; k < w; ++k) woff += ws[k];
    int excl = bsum[blockIdx.x] + woff + v - orig;
    if (i < n) {
        rowptr[i] = excl;
        counts[i] = excl;        // scatter cursor
    }
    if (blockIdx.x == 0 && t == 0) rowptr[n] = tot;
}

__global__ __launch_bounds__(256) void scatter_kernel(const int* __restrict__ ei,
                                                      int* __restrict__ cursor,
                                                      int* __restrict__ srcs, int E, int n) {
    int i = blockIdx.x * 256 + threadIdx.x;
    int tot = E + n;
    if (i >= tot) return;
    int s, d;
    if (i < E) { s = ei[i]; d = ei[E + i]; } else { s = i - E; d = s; }
    int pos = atomicAdd(&cursor[d], 1);
    srcs[pos] = s;
}

// ---------------- conversions ----------------

// x -> hi/lo bf16 split, 4 elems/thread
__global__ __launch_bounds__(256) void convsplit_kernel(const float* __restrict__ x,
                                                        unsigned short* __restrict__ hi,
                                                        unsigned short* __restrict__ lo,
                                                        int n4) {
    int i = blockIdx.x * 256 + threadIdx.x;
    if (i >= n4) return;
    float4 v = reinterpret_cast<const float4*>(x)[i];
    ushort2 h01, h23, l01, l23;
    float b;
    h01.x = bf16bits(v.x); b = bf16back(v.x); l01.x = bf16bits(v.x - b);
    h01.y = bf16bits(v.y); b = bf16back(v.y); l01.y = bf16bits(v.y - b);
    h23.x = bf16bits(v.z); b = bf16back(v.z); l23.x = bf16bits(v.z - b);
    h23.y = bf16bits(v.w); b = bf16back(v.w); l23.y = bf16bits(v.w - b);
    reinterpret_cast<ushort2*>(hi)[i * 2]     = h01;
    reinterpret_cast<ushort2*>(hi)[i * 2 + 1] = h23;
    reinterpret_cast<ushort2*>(lo)[i * 2]     = l01;
    reinterpret_cast<ushort2*>(lo)[i * 2 + 1] = l23;
}

// W [128 K][128 N] fp32 -> Bt [128 N][128 K] bf16 (transpose + round)
__global__ __launch_bounds__(256) void convWt_kernel(const float* __restrict__ W,
                                                     unsigned short* __restrict__ Bt) {
    int i = blockIdx.x * 256 + threadIdx.x;   // 16384
    int k = i >> 7, n = i & 127;
    Bt[n * 128 + k] = bf16bits(W[i]);
}

// ---------------- MFMA GEMM: Hb[M,128]bf16 = (Ahi+Alo)[M,128] @ B[128,128] ----------------

__global__ __launch_bounds__(256) void gemm_mfma(const unsigned short* __restrict__ Ahi,
                                                 const unsigned short* __restrict__ Alo,
                                                 const unsigned short* __restrict__ Bt,
                                                 unsigned short* __restrict__ Hb, int M) {
    __shared__ unsigned short Bs[128 * LDS_STRIDE];
    int t = threadIdx.x;
    for (int i = t; i < 128 * 16; i += 256) {
        int r = i >> 4, c = (i & 15) * 8;
        uint4 v = *reinterpret_cast<const uint4*>(Bt + r * 128 + c);
        *reinterpret_cast<uint4*>(&Bs[r * LDS_STRIDE + c]) = v;
    }
    __syncthreads();

    int wave = t >> 6, lane = t & 63;
    int m16 = lane & 15, quad = lane >> 4;
    int row0 = blockIdx.x * 64 + wave * 16;
    int arow = row0 + m16;
    if (arow > M - 1) arow = M - 1;           // clamp loads; stores predicated

    f32x4 acc[8] = {};
#pragma unroll
    for (int ks = 0; ks < 4; ++ks) {
        int k0 = ks * 32 + quad * 8;
        bf16x8 a_hi = __builtin_bit_cast(bf16x8,
            *reinterpret_cast<const uint4*>(Ahi + (size_t)arow * 128 + k0));
        bf16x8 a_lo = __builtin_bit_cast(bf16x8,
            *reinterpret_cast<const uint4*>(Alo + (size_t)arow * 128 + k0));
#pragma unroll
        for (int nt = 0; nt < 8; ++nt) {
            bf16x8 b = __builtin_bit_cast(bf16x8,
                *reinterpret_cast<const uint4*>(&Bs[(nt * 16 + m16) * LDS_STRIDE + k0]));
            acc[nt] = __builtin_amdgcn_mfma_f32_16x16x32_bf16(a_lo, b, acc[nt], 0, 0, 0);
            acc[nt] = __builtin_amdgcn_mfma_f32_16x16x32_bf16(a_hi, b, acc[nt], 0, 0, 0);
        }
    }
    // C/D layout: col = lane&15, row = quad*4 + reg   [m89-verified]
#pragma unroll
    for (int nt = 0; nt < 8; ++nt) {
#pragma unroll
        for (int r = 0; r < 4; ++r) {
            int gr = row0 + quad * 4 + r;
            if (gr < M) Hb[(size_t)gr * 128 + nt * 16 + m16] = bf16bits(acc[nt][r]);
        }
    }
}

// ---------------- attention coefficients (bf16 h input) ----------------

__global__ __launch_bounds__(256) void alpha1_kernel(const unsigned short* __restrict__ Hb,
                                                     const float* __restrict__ a_src,
                                                     const float* __restrict__ a_dst,
                                                     float* __restrict__ asrc,
                                                     float* __restrict__ adst, int n) {
    int idx = blockIdx.x * 256 + threadIdx.x;
    if (idx >= n * 4) return;
    int node = idx >> 2, h = idx & 3;
    const uint4* rp = reinterpret_cast<const uint4*>(Hb + (size_t)node * 128 + h * 32);
    const float* as = a_src + h * 32;
    const float* ad = a_dst + h * 32;
    float s1 = 0.f, s2 = 0.f;
#pragma unroll
    for (int q = 0; q < 4; ++q) {
        uint4 v = rp[q];
        float2 f0 = unpk(v.x), f1 = unpk(v.y), f2 = unpk(v.z), f3 = unpk(v.w);
        const float* aq = as + q * 8;
        const float* dq = ad + q * 8;
        s1 += f0.x * aq[0] + f0.y * aq[1] + f1.x * aq[2] + f1.y * aq[3]
            + f2.x * aq[4] + f2.y * aq[5] + f3.x * aq[6] + f3.y * aq[7];
        s2 += f0.x * dq[0] + f0.y * dq[1] + f1.x * dq[2] + f1.y * dq[3]
            + f2.x * dq[4] + f2.y * dq[5] + f3.x * dq[6] + f3.y * dq[7];
    }
    asrc[idx] = s1;
    adst[idx] = s2;
}

__global__ __launch_bounds__(256) void alpha2_kernel(const unsigned short* __restrict__ Hb,
                                                     const float* __restrict__ a_src,
                                                     const float* __restrict__ a_dst,
                                                     float* __restrict__ asrc,
                                                     float* __restrict__ adst, int n) {
    int wid = (blockIdx.x * 256 + threadIdx.x) >> 6;
    int lane = threadIdx.x & 63;
    if (wid >= n) return;
    const unsigned int* Hw = reinterpret_cast<const unsigned int*>(Hb);
    float2 hv = unpk(Hw[(size_t)wid * 64 + lane]);
    float2 a1 = reinterpret_cast<const float2*>(a_src)[lane];
    float2 a2 = reinterpret_cast<const float2*>(a_dst)[lane];
    float s1 = hv.x * a1.x + hv.y * a1.y;
    float s2 = hv.x * a2.x + hv.y * a2.y;
    for (int off = 32; off; off >>= 1) {
        s1 += __shfl_down(s1, off, 64);
        s2 += __shfl_down(s2, off, 64);
    }
    if (lane == 0) { asrc[wid] = s1; adst[wid] = s2; }
}

// ---------------- aggregation ----------------
// Lane decomposition (both agg kernels): m16 = lane&15 -> 8-channel group
// (16 B of the 256 B bf16 row); quad = lane>>4 -> edge slot. One dwordx4
// gather instruction covers 4 edges. Each lane computes its own exp weight
// (no per-edge shfl); den/acc quad-reduced once per node via shfl_xor.

// layer-1: 4 heads x 32 ch; head of channel-group = m16>>2.
// fused bias+ReLU; writes layer-2 input as bf16 hi/lo split.
__global__ __launch_bounds__(256) void agg1_kernel(const unsigned short* __restrict__ Hb,
                                                   const float* __restrict__ asrc,
                                                   const float* __restrict__ adst,
                                                   const int* __restrict__ rowptr,
                                                   const int* __restrict__ srcs,
                                                   const float* __restrict__ bias,
                                                   unsigned short* __restrict__ ohi,
                                                   unsigned short* __restrict__ olo, int n) {
    int wid = (blockIdx.x * 256 + threadIdx.x) >> 6;
    int lane = threadIdx.x & 63;
    if (wid >= n) return;
    int m16 = lane & 15, quad = lane >> 4;
    int hd = m16 >> 2;
    int d = wid;
    int beg = rowptr[d], end = rowptr[d + 1];
    float adh = adst[d * 4 + hd];
    const uint4* H4 = reinterpret_cast<const uint4*>(Hb);
    float acc[8] = {};
    float den = 0.f;

    auto body = [&](int p, bool chk) {
        int ep = p + quad;
        bool valid = !chk || (ep < end);
        int se = srcs[valid ? ep : beg];
        float e = asrc[se * 4 + hd] + adh;
        e = (e > 0.f) ? e : 0.2f * e;          // leaky_relu
        float pv = __expf(e);
        if (!valid) pv = 0.f;
        den += pv;
        uint4 hv = H4[(size_t)se * 16 + m16];
        float2 f0 = unpk(hv.x), f1 = unpk(hv.y), f2 = unpk(hv.z), f3 = unpk(hv.w);
        acc[0] += pv * f0.x; acc[1] += pv * f0.y;
        acc[2] += pv * f1.x; acc[3] += pv * f1.y;
        acc[4] += pv * f2.x; acc[5] += pv * f2.y;
        acc[6] += pv * f3.x; acc[7] += pv * f3.y;
    };
    int p = beg;
    for (; p + 8 <= end; p += 8) { body(p, false); body(p + 4, false); }
    for (; p < end; p += 4) body(p, true);

#pragma unroll
    for (int off = 16; off < 64; off <<= 1) {
        den += __shfl_xor(den, off, 64);
#pragma unroll
        for (int j = 0; j < 8; ++j) acc[j] += __shfl_xor(acc[j], off, 64);
    }
    float inv = 1.f / den;
    const float4* bv4 = reinterpret_cast<const float4*>(bias);
    float4 b0 = bv4[m16 * 2], b1 = bv4[m16 * 2 + 1];
    float v0 = fmaxf(b0.x + acc[0] * inv, 0.f);
    float v1 = fmaxf(b0.y + acc[1] * inv, 0.f);
    float v2 = fmaxf(b0.z + acc[2] * inv, 0.f);
    float v3 = fmaxf(b0.w + acc[3] * inv, 0.f);
    float v4 = fmaxf(b1.x + acc[4] * inv, 0.f);
    float v5 = fmaxf(b1.y + acc[5] * inv, 0.f);
    float v6 = fmaxf(b1.z + acc[6] * inv, 0.f);
    float v7 = fmaxf(b1.w + acc[7] * inv, 0.f);
    if (quad == 0) {
        uint4 hw;
        hw.x = pk2(v0, v1); hw.y = pk2(v2, v3); hw.z = pk2(v4, v5); hw.w = pk2(v6, v7);
        *reinterpret_cast<uint4*>(ohi + (size_t)d * 128 + m16 * 8) = hw;
    }
    if (quad == 1) {
        uint4 lw;
        lw.x = pk2(v0 - bf16back(v0), v1 - bf16back(v1));
        lw.y = pk2(v2 - bf16back(v2), v3 - bf16back(v3));
        lw.z = pk2(v4 - bf16back(v4), v5 - bf16back(v5));
        lw.w = pk2(v6 - bf16back(v6), v7 - bf16back(v7));
        *reinterpret_cast<uint4*>(olo + (size_t)d * 128 + m16 * 8) = lw;
    }
}

// layer-2: 1 head x 128 ch; + b2, no ReLU; fp32 output.
__global__ __launch_bounds__(256) void agg2_kernel(const unsigned short* __restrict__ Hb,
                                                   const float* __restrict__ asrc,
                                                   const float* __restrict__ adst,
                                                   const int* __restrict__ rowptr,
                                                   const int* __restrict__ srcs,
                                                   const float* __restrict__ bias,
                                                   float* __restrict__ out, int n) {
    int wid = (blockIdx.x * 256 + threadIdx.x) >> 6;
    int lane = threadIdx.x & 63;
    if (wid >= n) return;
    int m16 = lane & 15, quad = lane >> 4;
    int d = wid;
    int beg = rowptr[d], end = rowptr[d + 1];
    float ad = adst[d];
    const uint4* H4 = reinterpret_cast<const uint4*>(Hb);
    float acc[8] = {};
    float den = 0.f;

    auto body = [&](int p, bool chk) {
        int ep = p + quad;
        bool valid = !chk || (ep < end);
        int se = srcs[valid ? ep : beg];
        float e = asrc[se] + ad;
        e = (e > 0.f) ? e : 0.2f * e;
        float pv = __expf(e);
        if (!valid) pv = 0.f;
        den += pv;
        uint4 hv = H4[(size_t)se * 16 + m16];
        float2 f0 = unpk(hv.x), f1 = unpk(hv.y), f2 = unpk(hv.z), f3 = unpk(hv.w);
        acc[0] += pv * f0.x; acc[1] += pv * f0.y;
        acc[2] += pv * f1.x; acc[3] += pv * f1.y;
        acc[4] += pv * f2.x; acc[5] += pv * f2.y;
        acc[6] += pv * f3.x; acc[7] += pv * f3.y;
    };
    int p = beg;
    for (; p + 8 <= end; p += 8) { body(p, false); body(p + 4, false); }
    for (; p < end; p += 4) body(p, true);

#pragma unroll
    for (int off = 16; off < 64; off <<= 1) {
        den += __shfl_xor(den, off, 64);
#pragma unroll
        for (int j = 0; j < 8; ++j) acc[j] += __shfl_xor(acc[j], off, 64);
    }
    float inv = 1.f / den;
    const float4* bv4 = reinterpret_cast<const float4*>(bias);
    float4 b0 = bv4[m16 * 2], b1 = bv4[m16 * 2 + 1];
    if (quad == 0) {
        float4 o;
        o.x = b0.x + acc[0] * inv; o.y = b0.y + acc[1] * inv;
        o.z = b0.z + acc[2] * inv; o.w = b0.w + acc[3] * inv;
        *reinterpret_cast<float4*>(out + (size_t)d * 128 + m16 * 8) = o;
    }
    if (quad == 1) {
        float4 o;
        o.x = b1.x + acc[4] * inv; o.y = b1.y + acc[5] * inv;
        o.z = b1.z + acc[6] * inv; o.w = b1.w + acc[7] * inv;
        *reinterpret_cast<float4*>(out + (size_t)d * 128 + m16 * 8 + 4) = o;
    }
}

// ---------------- launch ----------------

extern "C" void kernel_launch(void* const* d_in, const int* in_sizes, int n_in,
                              void* d_out, int out_size, void* d_ws, size_t ws_size,
                              hipStream_t stream) {
    const float* x   = (const float*)d_in[0];
    const int*   ei  = (const int*)d_in[1];
    const float* W1  = (const float*)d_in[2];
    const float* as1 = (const float*)d_in[3];
    const float* ad1 = (const float*)d_in[4];
    const float* b1  = (const float*)d_in[5];
    const float* W2  = (const float*)d_in[6];
    const float* as2 = (const float*)d_in[7];
    const float* ad2 = (const float*)d_in[8];
    const float* b2  = (const float*)d_in[9];

    int N = in_sizes[0] / 128;
    int E = in_sizes[1] / 2;
    int tot = E + N;
    int nb = (N + 255) / 256;   // scan blocks (<=256 required; N=50k -> 196)

    char* wsb = (char*)d_ws;
    size_t off = 0;
    auto alloc = [&](size_t bytes) {
        void* p = wsb + off;
        off += (bytes + 255) & ~(size_t)255;
        return p;
    };
    unsigned short* Ahi = (unsigned short*)alloc((size_t)N * 128 * 2); // x_hi; reused as out1_hi
    unsigned short* Alo = (unsigned short*)alloc((size_t)N * 128 * 2); // x_lo; reused as out1_lo
    unsigned short* Hb  = (unsigned short*)alloc((size_t)N * 128 * 2); // h bf16 (h1 then h2)
    unsigned short* Bt1 = (unsigned short*)alloc(128 * 128 * 2);
    unsigned short* Bt2 = (unsigned short*)alloc(128 * 128 * 2);
    int*   counts = (int*)alloc((size_t)N * 4);
    int*   rowptr = (int*)alloc((size_t)(N + 1) * 4);
    int*   srcs   = (int*)alloc((size_t)tot * 4);
    int*   bsum   = (int*)alloc(256 * 4);
    float* asrc1  = (float*)alloc((size_t)N * 4 * 4);
    float* adst1  = (float*)alloc((size_t)N * 4 * 4);
    float* asrc2  = (float*)alloc((size_t)N * 4);
    float* adst2  = (float*)alloc((size_t)N * 4);
    (void)ws_size; (void)n_in; (void)out_size;

    // CSR by dst (shared by both layers) — parallel 3-stage scan
    hipMemsetAsync(counts, 0, (size_t)N * 4, stream);
    hist_kernel<<<(tot + 255) / 256, 256, 0, stream>>>(ei, counts, E, N);
    scan_partial<<<nb, 256, 0, stream>>>(counts, bsum, N);
    scan_bsums<<<1, 256, 0, stream>>>(bsum, nb);
    scan_final<<<nb, 256, 0, stream>>>(counts, bsum, rowptr, N, tot);
    scatter_kernel<<<(tot + 255) / 256, 256, 0, stream>>>(ei, counts, srcs, E, N);

    // conversions
    int n4 = N * 128 / 4;
    convsplit_kernel<<<(n4 + 255) / 256, 256, 0, stream>>>(x, Ahi, Alo, n4);
    convWt_kernel<<<64, 256, 0, stream>>>(W1, Bt1);
    convWt_kernel<<<64, 256, 0, stream>>>(W2, Bt2);

    int gblocks = (N + 63) / 64;

    // layer 1
    gemm_mfma<<<gblocks, 256, 0, stream>>>(Ahi, Alo, Bt1, Hb, N);
    alpha1_kernel<<<(N * 4 + 255) / 256, 256, 0, stream>>>(Hb, as1, ad1, asrc1, adst1, N);
    agg1_kernel<<<(N + 3) / 4, 256, 0, stream>>>(Hb, asrc1, adst1, rowptr, srcs, b1,
                                                 Ahi, Alo, N);   // out1 -> Ahi/Alo (reuse)

    // layer 2
    gemm_mfma<<<gblocks, 256, 0, stream>>>(Ahi, Alo, Bt2, Hb, N);
    alpha2_kernel<<<(N + 3) / 4, 256, 0, stream>>>(Hb, as2, ad2, asrc2, adst2, N);
    agg2_kernel<<<(N + 3) / 4, 256, 0, stream>>>(Hb, asrc2, adst2, rowptr, srcs, b2,
                                                 (float*)d_out, N);
}

// Round 6
// 278.335 us; speedup vs baseline: 2.8297x; 1.0928x over previous
//
#include <hip/hip_runtime.h>
#include <hip/hip_bf16.h>

// ---------------------------------------------------------------------------
// 2-layer GAT on MI355X (gfx950).
//   CSR-by-dst build: hist+rank (one atomic pass) / 3-stage parallel scan /
//   atomic-free dst-partitioned scatter (XCD-swizzled, 8 groups) so each srcs
//   partition is written by ~one XCD's L2 -> kills the 16x write amplification
//   seen in r5 (WRITE_SIZE 54 MB for a 3.4 MB payload).
//   GEMMs on the MFMA bf16 pipe with 2-term A-split (A_hi + A_lo).
//   h stored as packed bf16 (256 B/row).
//   agg kernels: lane = (channel-group, edge-slot); one dwordx4 gather covers
//   4 edges; per-lane exp; quad-reduce once per node.
//   Softmax without segment-max (scale-invariant; exponents bounded ~|10|).
// ---------------------------------------------------------------------------

typedef __attribute__((ext_vector_type(8))) short bf16x8;
typedef __attribute__((ext_vector_type(4))) float f32x4;

#define LDS_STRIDE 136  // 128 + 8 pad (bf16): row stride 68 dwords -> 2-way max (free)
#define SCAT_CH 4096    // edges per scatter block (256 threads x 16)

__device__ inline unsigned short bf16bits(float v) {
    __hip_bfloat16 h = __float2bfloat16(v);
    return __builtin_bit_cast(unsigned short, h);
}
__device__ inline float bf16back(float v) {
    __hip_bfloat16 h = __float2bfloat16(v);
    return __bfloat162float(h);
}
// packed pair (lo 16 bits = elem0, hi = elem1) -> two fp32
__device__ inline float2 unpk(unsigned int u) {
    float2 r;
    r.x = __builtin_bit_cast(float, u << 16);
    r.y = __builtin_bit_cast(float, u & 0xffff0000u);
    return r;
}
__device__ inline unsigned int pk2(float a, float b) {
    return (unsigned int)bf16bits(a) | ((unsigned int)bf16bits(b) << 16);
}

// ---------------- CSR build ----------------

// one atomic pass: per-dst count AND per-edge rank (coalesced write)
__global__ __launch_bounds__(256) void hist_rank(const int* __restrict__ ei,
                                                 int* __restrict__ counts,
                                                 int* __restrict__ rank, int E, int n) {
    int i = blockIdx.x * 256 + threadIdx.x;
    int tot = E + n;
    if (i >= tot) return;
    int d = (i < E) ? ei[E + i] : (i - E);   // self-loops appended at the end
    int r = atomicAdd(&counts[d], 1);
    rank[i] = r;
}

// stage 1: per-block (256-elem chunk) reduction -> bsum[b]
__global__ __launch_bounds__(256) void scan_partial(const int* __restrict__ counts,
                                                    int* __restrict__ bsum, int n) {
    int t = threadIdx.x;
    int i = blockIdx.x * 256 + t;
    int v = (i < n) ? counts[i] : 0;
    for (int off = 32; off; off >>= 1) v += __shfl_down(v, off, 64);
    __shared__ int ws[4];
    if ((t & 63) == 0) ws[t >> 6] = v;
    __syncthreads();
    if (t == 0) bsum[blockIdx.x] = ws[0] + ws[1] + ws[2] + ws[3];
}

// stage 2: single block, exclusive scan of nb (<=256) block sums in place
__global__ __launch_bounds__(256) void scan_bsums(int* __restrict__ bsum, int nb) {
    int t = threadIdx.x;
    int lane = t & 63, w = t >> 6;
    int orig = (t < nb) ? bsum[t] : 0;
    int v = orig;
    for (int off = 1; off < 64; off <<= 1) {
        int u = __shfl_up(v, off, 64);
        if (lane >= off) v += u;
    }
    __shared__ int ws[4];
    if (lane == 63) ws[w] = v;
    __syncthreads();
    int woff = 0;
    for (int i = 0; i < w; ++i) woff += ws[i];
    if (t < nb) bsum[t] = woff + v - orig;   // exclusive
}

// stage 3: in-block exclusive scan + block offset -> rowptr
__global__ __launch_bounds__(256) void scan_final(const int* __restrict__ counts,
                                                  const int* __restrict__ bsum,
                                                  int* __restrict__ rowptr, int n, int tot) {
    int t = threadIdx.x;
    int i = blockIdx.x * 256 + t;
    int lane = t & 63, w = t >> 6;
    int orig = (i < n) ? counts[i] : 0;
    int v = orig;
    for (int off = 1; off < 64; off <<= 1) {
        int u = __shfl_up(v, off, 64);
        if (lane >= off) v += u;
    }
    __shared__ int ws[4];
    if (lane == 63) ws[w] = v;
    __syncthreads();
    int woff = 0;
    for (int k = 0; k < w; ++k) woff += ws[k];
    int excl = bsum[blockIdx.x] + woff + v - orig;
    if (i < n) rowptr[i] = excl;
    if (blockIdx.x == 0 && t == 0) rowptr[n] = tot;
}

// atomic-free scatter, dst-partitioned into 8 groups (XCD swizzle: blockIdx&7).
// Each group writes only dsts in its contiguous 1/8 node range -> each srcs
// partition is written by blocks of (heuristically) one XCD; correctness does
// not depend on the actual XCD mapping.
__global__ __launch_bounds__(256) void scatter_part(const int* __restrict__ ei,
                                                    const int* __restrict__ rowptr,
                                                    const int* __restrict__ rank,
                                                    int* __restrict__ srcs, int E, int n) {
    int b = blockIdx.x;
    int part = b & 7;
    int base = (b >> 3) * SCAT_CH;
    int tot = E + n;
    int thr = (n + 7) >> 3;
    int lo = part * thr;
    int hi = lo + thr; if (hi > n) hi = n;
#pragma unroll
    for (int j = 0; j < SCAT_CH / 256; ++j) {
        int i = base + j * 256 + threadIdx.x;
        if (i >= tot) continue;
        int d = (i < E) ? ei[E + i] : (i - E);
        if (d < lo || d >= hi) continue;
        int s = (i < E) ? ei[i] : d;
        srcs[rowptr[d] + rank[i]] = s;
    }
}

// ---------------- conversions ----------------

// x -> hi/lo bf16 split, 4 elems/thread
__global__ __launch_bounds__(256) void convsplit_kernel(const float* __restrict__ x,
                                                        unsigned short* __restrict__ hi,
                                                        unsigned short* __restrict__ lo,
                                                        int n4) {
    int i = blockIdx.x * 256 + threadIdx.x;
    if (i >= n4) return;
    float4 v = reinterpret_cast<const float4*>(x)[i];
    ushort2 h01, h23, l01, l23;
    float b;
    h01.x = bf16bits(v.x); b = bf16back(v.x); l01.x = bf16bits(v.x - b);
    h01.y = bf16bits(v.y); b = bf16back(v.y); l01.y = bf16bits(v.y - b);
    h23.x = bf16bits(v.z); b = bf16back(v.z); l23.x = bf16bits(v.z - b);
    h23.y = bf16bits(v.w); b = bf16back(v.w); l23.y = bf16bits(v.w - b);
    reinterpret_cast<ushort2*>(hi)[i * 2]     = h01;
    reinterpret_cast<ushort2*>(hi)[i * 2 + 1] = h23;
    reinterpret_cast<ushort2*>(lo)[i * 2]     = l01;
    reinterpret_cast<ushort2*>(lo)[i * 2 + 1] = l23;
}

// W [128 K][128 N] fp32 -> Bt [128 N][128 K] bf16 (transpose + round)
__global__ __launch_bounds__(256) void convWt_kernel(const float* __restrict__ W,
                                                     unsigned short* __restrict__ Bt) {
    int i = blockIdx.x * 256 + threadIdx.x;   // 16384
    int k = i >> 7, n = i & 127;
    Bt[n * 128 + k] = bf16bits(W[i]);
}

// ---------------- MFMA GEMM: Hb[M,128]bf16 = (Ahi+Alo)[M,128] @ B[128,128] ----------------

__global__ __launch_bounds__(256) void gemm_mfma(const unsigned short* __restrict__ Ahi,
                                                 const unsigned short* __restrict__ Alo,
                                                 const unsigned short* __restrict__ Bt,
                                                 unsigned short* __restrict__ Hb, int M) {
    __shared__ unsigned short Bs[128 * LDS_STRIDE];
    int t = threadIdx.x;
    for (int i = t; i < 128 * 16; i += 256) {
        int r = i >> 4, c = (i & 15) * 8;
        uint4 v = *reinterpret_cast<const uint4*>(Bt + r * 128 + c);
        *reinterpret_cast<uint4*>(&Bs[r * LDS_STRIDE + c]) = v;
    }
    __syncthreads();

    int wave = t >> 6, lane = t & 63;
    int m16 = lane & 15, quad = lane >> 4;
    int row0 = blockIdx.x * 64 + wave * 16;
    int arow = row0 + m16;
    if (arow > M - 1) arow = M - 1;           // clamp loads; stores predicated

    f32x4 acc[8] = {};
#pragma unroll
    for (int ks = 0; ks < 4; ++ks) {
        int k0 = ks * 32 + quad * 8;
        bf16x8 a_hi = __builtin_bit_cast(bf16x8,
            *reinterpret_cast<const uint4*>(Ahi + (size_t)arow * 128 + k0));
        bf16x8 a_lo = __builtin_bit_cast(bf16x8,
            *reinterpret_cast<const uint4*>(Alo + (size_t)arow * 128 + k0));
#pragma unroll
        for (int nt = 0; nt < 8; ++nt) {
            bf16x8 b = __builtin_bit_cast(bf16x8,
                *reinterpret_cast<const uint4*>(&Bs[(nt * 16 + m16) * LDS_STRIDE + k0]));
            acc[nt] = __builtin_amdgcn_mfma_f32_16x16x32_bf16(a_lo, b, acc[nt], 0, 0, 0);
            acc[nt] = __builtin_amdgcn_mfma_f32_16x16x32_bf16(a_hi, b, acc[nt], 0, 0, 0);
        }
    }
    // C/D layout: col = lane&15, row = quad*4 + reg   [m89-verified]
#pragma unroll
    for (int nt = 0; nt < 8; ++nt) {
#pragma unroll
        for (int r = 0; r < 4; ++r) {
            int gr = row0 + quad * 4 + r;
            if (gr < M) Hb[(size_t)gr * 128 + nt * 16 + m16] = bf16bits(acc[nt][r]);
        }
    }
}

// ---------------- attention coefficients (bf16 h input) ----------------

__global__ __launch_bounds__(256) void alpha1_kernel(const unsigned short* __restrict__ Hb,
                                                     const float* __restrict__ a_src,
                                                     const float* __restrict__ a_dst,
                                                     float* __restrict__ asrc,
                                                     float* __restrict__ adst, int n) {
    int idx = blockIdx.x * 256 + threadIdx.x;
    if (idx >= n * 4) return;
    int node = idx >> 2, h = idx & 3;
    const uint4* rp = reinterpret_cast<const uint4*>(Hb + (size_t)node * 128 + h * 32);
    const float* as = a_src + h * 32;
    const float* ad = a_dst + h * 32;
    float s1 = 0.f, s2 = 0.f;
#pragma unroll
    for (int q = 0; q < 4; ++q) {
        uint4 v = rp[q];
        float2 f0 = unpk(v.x), f1 = unpk(v.y), f2 = unpk(v.z), f3 = unpk(v.w);
        const float* aq = as + q * 8;
        const float* dq = ad + q * 8;
        s1 += f0.x * aq[0] + f0.y * aq[1] + f1.x * aq[2] + f1.y * aq[3]
            + f2.x * aq[4] + f2.y * aq[5] + f3.x * aq[6] + f3.y * aq[7];
        s2 += f0.x * dq[0] + f0.y * dq[1] + f1.x * dq[2] + f1.y * dq[3]
            + f2.x * dq[4] + f2.y * dq[5] + f3.x * dq[6] + f3.y * dq[7];
    }
    asrc[idx] = s1;
    adst[idx] = s2;
}

__global__ __launch_bounds__(256) void alpha2_kernel(const unsigned short* __restrict__ Hb,
                                                     const float* __restrict__ a_src,
                                                     const float* __restrict__ a_dst,
                                                     float* __restrict__ asrc,
                                                     float* __restrict__ adst, int n) {
    int wid = (blockIdx.x * 256 + threadIdx.x) >> 6;
    int lane = threadIdx.x & 63;
    if (wid >= n) return;
    const unsigned int* Hw = reinterpret_cast<const unsigned int*>(Hb);
    float2 hv = unpk(Hw[(size_t)wid * 64 + lane]);
    float2 a1 = reinterpret_cast<const float2*>(a_src)[lane];
    float2 a2 = reinterpret_cast<const float2*>(a_dst)[lane];
    float s1 = hv.x * a1.x + hv.y * a1.y;
    float s2 = hv.x * a2.x + hv.y * a2.y;
    for (int off = 32; off; off >>= 1) {
        s1 += __shfl_down(s1, off, 64);
        s2 += __shfl_down(s2, off, 64);
    }
    if (lane == 0) { asrc[wid] = s1; adst[wid] = s2; }
}

// ---------------- aggregation ----------------
// Lane decomposition: m16 = lane&15 -> 8-channel group (16 B of the 256 B
// row); quad = lane>>4 -> edge slot. One dwordx4 gather covers 4 edges.
// Per-lane exp (no per-edge shfl); den/acc quad-reduced once per node.

// layer-1: 4 heads x 32 ch; head of channel-group = m16>>2.
// fused bias+ReLU; writes layer-2 input as bf16 hi/lo split.
__global__ __launch_bounds__(256) void agg1_kernel(const unsigned short* __restrict__ Hb,
                                                   const float* __restrict__ asrc,
                                                   const float* __restrict__ adst,
                                                   const int* __restrict__ rowptr,
                                                   const int* __restrict__ srcs,
                                                   const float* __restrict__ bias,
                                                   unsigned short* __restrict__ ohi,
                                                   unsigned short* __restrict__ olo, int n) {
    int wid = (blockIdx.x * 256 + threadIdx.x) >> 6;
    int lane = threadIdx.x & 63;
    if (wid >= n) return;
    int m16 = lane & 15, quad = lane >> 4;
    int hd = m16 >> 2;
    int d = wid;
    int beg = rowptr[d], end = rowptr[d + 1];
    float adh = adst[d * 4 + hd];
    const uint4* H4 = reinterpret_cast<const uint4*>(Hb);
    float acc[8] = {};
    float den = 0.f;

    auto body = [&](int p, bool chk) {
        int ep = p + quad;
        bool valid = !chk || (ep < end);
        int se = srcs[valid ? ep : beg];
        float e = asrc[se * 4 + hd] + adh;
        e = (e > 0.f) ? e : 0.2f * e;          // leaky_relu
        float pv = __expf(e);
        if (!valid) pv = 0.f;
        den += pv;
        uint4 hv = H4[(size_t)se * 16 + m16];
        float2 f0 = unpk(hv.x), f1 = unpk(hv.y), f2 = unpk(hv.z), f3 = unpk(hv.w);
        acc[0] += pv * f0.x; acc[1] += pv * f0.y;
        acc[2] += pv * f1.x; acc[3] += pv * f1.y;
        acc[4] += pv * f2.x; acc[5] += pv * f2.y;
        acc[6] += pv * f3.x; acc[7] += pv * f3.y;
    };
    int p = beg;
    for (; p + 8 <= end; p += 8) { body(p, false); body(p + 4, false); }
    for (; p < end; p += 4) body(p, true);

#pragma unroll
    for (int off = 16; off < 64; off <<= 1) {
        den += __shfl_xor(den, off, 64);
#pragma unroll
        for (int j = 0; j < 8; ++j) acc[j] += __shfl_xor(acc[j], off, 64);
    }
    float inv = 1.f / den;
    const float4* bv4 = reinterpret_cast<const float4*>(bias);
    float4 b0 = bv4[m16 * 2], b1 = bv4[m16 * 2 + 1];
    float v0 = fmaxf(b0.x + acc[0] * inv, 0.f);
    float v1 = fmaxf(b0.y + acc[1] * inv, 0.f);
    float v2 = fmaxf(b0.z + acc[2] * inv, 0.f);
    float v3 = fmaxf(b0.w + acc[3] * inv, 0.f);
    float v4 = fmaxf(b1.x + acc[4] * inv, 0.f);
    float v5 = fmaxf(b1.y + acc[5] * inv, 0.f);
    float v6 = fmaxf(b1.z + acc[6] * inv, 0.f);
    float v7 = fmaxf(b1.w + acc[7] * inv, 0.f);
    if (quad == 0) {
        uint4 hw;
        hw.x = pk2(v0, v1); hw.y = pk2(v2, v3); hw.z = pk2(v4, v5); hw.w = pk2(v6, v7);
        *reinterpret_cast<uint4*>(ohi + (size_t)d * 128 + m16 * 8) = hw;
    }
    if (quad == 1) {
        uint4 lw;
        lw.x = pk2(v0 - bf16back(v0), v1 - bf16back(v1));
        lw.y = pk2(v2 - bf16back(v2), v3 - bf16back(v3));
        lw.z = pk2(v4 - bf16back(v4), v5 - bf16back(v5));
        lw.w = pk2(v6 - bf16back(v6), v7 - bf16back(v7));
        *reinterpret_cast<uint4*>(olo + (size_t)d * 128 + m16 * 8) = lw;
    }
}

// layer-2: 1 head x 128 ch; + b2, no ReLU; fp32 output.
__global__ __launch_bounds__(256) void agg2_kernel(const unsigned short* __restrict__ Hb,
                                                   const float* __restrict__ asrc,
                                                   const float* __restrict__ adst,
                                                   const int* __restrict__ rowptr,
                                                   const int* __restrict__ srcs,
                                                   const float* __restrict__ bias,
                                                   float* __restrict__ out, int n) {
    int wid = (blockIdx.x * 256 + threadIdx.x) >> 6;
    int lane = threadIdx.x & 63;
    if (wid >= n) return;
    int m16 = lane & 15, quad = lane >> 4;
    int d = wid;
    int beg = rowptr[d], end = rowptr[d + 1];
    float ad = adst[d];
    const uint4* H4 = reinterpret_cast<const uint4*>(Hb);
    float acc[8] = {};
    float den = 0.f;

    auto body = [&](int p, bool chk) {
        int ep = p + quad;
        bool valid = !chk || (ep < end);
        int se = srcs[valid ? ep : beg];
        float e = asrc[se] + ad;
        e = (e > 0.f) ? e : 0.2f * e;
        float pv = __expf(e);
        if (!valid) pv = 0.f;
        den += pv;
        uint4 hv = H4[(size_t)se * 16 + m16];
        float2 f0 = unpk(hv.x), f1 = unpk(hv.y), f2 = unpk(hv.z), f3 = unpk(hv.w);
        acc[0] += pv * f0.x; acc[1] += pv * f0.y;
        acc[2] += pv * f1.x; acc[3] += pv * f1.y;
        acc[4] += pv * f2.x; acc[5] += pv * f2.y;
        acc[6] += pv * f3.x; acc[7] += pv * f3.y;
    };
    int p = beg;
    for (; p + 8 <= end; p += 8) { body(p, false); body(p + 4, false); }
    for (; p < end; p += 4) body(p, true);

#pragma unroll
    for (int off = 16; off < 64; off <<= 1) {
        den += __shfl_xor(den, off, 64);
#pragma unroll
        for (int j = 0; j < 8; ++j) acc[j] += __shfl_xor(acc[j], off, 64);
    }
    float inv = 1.f / den;
    const float4* bv4 = reinterpret_cast<const float4*>(bias);
    float4 b0 = bv4[m16 * 2], b1 = bv4[m16 * 2 + 1];
    if (quad == 0) {
        float4 o;
        o.x = b0.x + acc[0] * inv; o.y = b0.y + acc[1] * inv;
        o.z = b0.z + acc[2] * inv; o.w = b0.w + acc[3] * inv;
        *reinterpret_cast<float4*>(out + (size_t)d * 128 + m16 * 8) = o;
    }
    if (quad == 1) {
        float4 o;
        o.x = b1.x + acc[4] * inv; o.y = b1.y + acc[5] * inv;
        o.z = b1.z + acc[6] * inv; o.w = b1.w + acc[7] * inv;
        *reinterpret_cast<float4*>(out + (size_t)d * 128 + m16 * 8 + 4) = o;
    }
}

// ---------------- launch ----------------

extern "C" void kernel_launch(void* const* d_in, const int* in_sizes, int n_in,
                              void* d_out, int out_size, void* d_ws, size_t ws_size,
                              hipStream_t stream) {
    const float* x   = (const float*)d_in[0];
    const int*   ei  = (const int*)d_in[1];
    const float* W1  = (const float*)d_in[2];
    const float* as1 = (const float*)d_in[3];
    const float* ad1 = (const float*)d_in[4];
    const float* b1  = (const float*)d_in[5];
    const float* W2  = (const float*)d_in[6];
    const float* as2 = (const float*)d_in[7];
    const float* ad2 = (const float*)d_in[8];
    const float* b2  = (const float*)d_in[9];

    int N = in_sizes[0] / 128;
    int E = in_sizes[1] / 2;
    int tot = E + N;
    int nb = (N + 255) / 256;           // scan blocks (<=256 required; N=50k -> 196)
    int nscat = (tot + SCAT_CH - 1) / SCAT_CH;

    char* wsb = (char*)d_ws;
    size_t off = 0;
    auto alloc = [&](size_t bytes) {
        void* p = wsb + off;
        off += (bytes + 255) & ~(size_t)255;
        return p;
    };
    unsigned short* Ahi = (unsigned short*)alloc((size_t)N * 128 * 2); // x_hi; reused as out1_hi
    unsigned short* Alo = (unsigned short*)alloc((size_t)N * 128 * 2); // x_lo; reused as out1_lo
    unsigned short* Hb  = (unsigned short*)alloc((size_t)N * 128 * 2); // h bf16 (h1 then h2)
    unsigned short* Bt1 = (unsigned short*)alloc(128 * 128 * 2);
    unsigned short* Bt2 = (unsigned short*)alloc(128 * 128 * 2);
    int*   counts = (int*)alloc((size_t)N * 4);
    int*   rowptr = (int*)alloc((size_t)(N + 1) * 4);
    int*   srcs   = (int*)alloc((size_t)tot * 4);
    int*   rank   = (int*)alloc((size_t)tot * 4);
    int*   bsum   = (int*)alloc(256 * 4);
    float* asrc1  = (float*)alloc((size_t)N * 4 * 4);
    float* adst1  = (float*)alloc((size_t)N * 4 * 4);
    float* asrc2  = (float*)alloc((size_t)N * 4);
    float* adst2  = (float*)alloc((size_t)N * 4);
    (void)ws_size; (void)n_in; (void)out_size;

    // CSR by dst (shared by both layers)
    hipMemsetAsync(counts, 0, (size_t)N * 4, stream);
    hist_rank<<<(tot + 255) / 256, 256, 0, stream>>>(ei, counts, rank, E, N);
    scan_partial<<<nb, 256, 0, stream>>>(counts, bsum, N);
    scan_bsums<<<1, 256, 0, stream>>>(bsum, nb);
    scan_final<<<nb, 256, 0, stream>>>(counts, bsum, rowptr, N, tot);
    scatter_part<<<nscat * 8, 256, 0, stream>>>(ei, rowptr, rank, srcs, E, N);

    // conversions
    int n4 = N * 128 / 4;
    convsplit_kernel<<<(n4 + 255) / 256, 256, 0, stream>>>(x, Ahi, Alo, n4);
    convWt_kernel<<<64, 256, 0, stream>>>(W1, Bt1);
    convWt_kernel<<<64, 256, 0, stream>>>(W2, Bt2);

    int gblocks = (N + 63) / 64;

    // layer 1
    gemm_mfma<<<gblocks, 256, 0, stream>>>(Ahi, Alo, Bt1, Hb, N);
    alpha1_kernel<<<(N * 4 + 255) / 256, 256, 0, stream>>>(Hb, as1, ad1, asrc1, adst1, N);
    agg1_kernel<<<(N + 3) / 4, 256, 0, stream>>>(Hb, asrc1, adst1, rowptr, srcs, b1,
                                                 Ahi, Alo, N);   // out1 -> Ahi/Alo (reuse)

    // layer 2
    gemm_mfma<<<gblocks, 256, 0, stream>>>(Ahi, Alo, Bt2, Hb, N);
    alpha2_kernel<<<(N + 3) / 4, 256, 0, stream>>>(Hb, as2, ad2, asrc2, adst2, N);
    agg2_kernel<<<(N + 3) / 4, 256, 0, stream>>>(Hb, asrc2, adst2, rowptr, srcs, b2,
                                                 (float*)d_out, N);
}

// Round 7
// 256.568 us; speedup vs baseline: 3.0697x; 1.0848x over previous
//
#include <hip/hip_runtime.h>
#include <hip/hip_bf16.h>

// ---------------------------------------------------------------------------
// 2-layer GAT on MI355X (gfx950).
//   CSR-by-dst: hist+rank (one atomic pass) / 3-stage parallel scan /
//   atomic-free dst-partitioned scatter (8-way XCD swizzle).
//   gemm1: fp32 x -> in-register bf16 hi/lo split -> MFMA (2-term A-split);
//          epilogue writes Hb (bf16) AND alpha1 (fused att dot + quad-reduce).
//   gemm2: bf16 hi/lo input (written by agg1); epilogue fuses alpha2.
//   agg kernels: lane = (channel-group m16, edge-slot quad); one dwordx4
//   gather covers 4 edges; per-lane exp; quad-reduce once per node.
//   Softmax without segment-max (scale-invariant; exponents bounded ~|10|).
// ---------------------------------------------------------------------------

typedef __attribute__((ext_vector_type(8))) short bf16x8;
typedef __attribute__((ext_vector_type(4))) float f32x4;

#define LDS_STRIDE 136  // 128 + 8 pad (bf16): row stride 68 dwords -> 2-way max (free)
#define SCAT_CH 4096    // edges per scatter block (256 threads x 16)

__device__ inline unsigned short bf16bits(float v) {
    __hip_bfloat16 h = __float2bfloat16(v);
    return __builtin_bit_cast(unsigned short, h);
}
__device__ inline float bf16back(float v) {
    __hip_bfloat16 h = __float2bfloat16(v);
    return __bfloat162float(h);
}
// packed pair (lo 16 bits = elem0, hi = elem1) -> two fp32
__device__ inline float2 unpk(unsigned int u) {
    float2 r;
    r.x = __builtin_bit_cast(float, u << 16);
    r.y = __builtin_bit_cast(float, u & 0xffff0000u);
    return r;
}
__device__ inline unsigned int pk2(float a, float b) {
    return (unsigned int)bf16bits(a) | ((unsigned int)bf16bits(b) << 16);
}

// ---------------- CSR build ----------------

__global__ __launch_bounds__(256) void hist_rank(const int* __restrict__ ei,
                                                 int* __restrict__ counts,
                                                 int* __restrict__ rank, int E, int n) {
    int i = blockIdx.x * 256 + threadIdx.x;
    int tot = E + n;
    if (i >= tot) return;
    int d = (i < E) ? ei[E + i] : (i - E);   // self-loops appended at the end
    int r = atomicAdd(&counts[d], 1);
    rank[i] = r;
}

__global__ __launch_bounds__(256) void scan_partial(const int* __restrict__ counts,
                                                    int* __restrict__ bsum, int n) {
    int t = threadIdx.x;
    int i = blockIdx.x * 256 + t;
    int v = (i < n) ? counts[i] : 0;
    for (int off = 32; off; off >>= 1) v += __shfl_down(v, off, 64);
    __shared__ int ws[4];
    if ((t & 63) == 0) ws[t >> 6] = v;
    __syncthreads();
    if (t == 0) bsum[blockIdx.x] = ws[0] + ws[1] + ws[2] + ws[3];
}

__global__ __launch_bounds__(256) void scan_bsums(int* __restrict__ bsum, int nb) {
    int t = threadIdx.x;
    int lane = t & 63, w = t >> 6;
    int orig = (t < nb) ? bsum[t] : 0;
    int v = orig;
    for (int off = 1; off < 64; off <<= 1) {
        int u = __shfl_up(v, off, 64);
        if (lane >= off) v += u;
    }
    __shared__ int ws[4];
    if (lane == 63) ws[w] = v;
    __syncthreads();
    int woff = 0;
    for (int i = 0; i < w; ++i) woff += ws[i];
    if (t < nb) bsum[t] = woff + v - orig;   // exclusive
}

__global__ __launch_bounds__(256) void scan_final(const int* __restrict__ counts,
                                                  const int* __restrict__ bsum,
                                                  int* __restrict__ rowptr, int n, int tot) {
    int t = threadIdx.x;
    int i = blockIdx.x * 256 + t;
    int lane = t & 63, w = t >> 6;
    int orig = (i < n) ? counts[i] : 0;
    int v = orig;
    for (int off = 1; off < 64; off <<= 1) {
        int u = __shfl_up(v, off, 64);
        if (lane >= off) v += u;
    }
    __shared__ int ws[4];
    if (lane == 63) ws[w] = v;
    __syncthreads();
    int woff = 0;
    for (int k = 0; k < w; ++k) woff += ws[k];
    int excl = bsum[blockIdx.x] + woff + v - orig;
    if (i < n) rowptr[i] = excl;
    if (blockIdx.x == 0 && t == 0) rowptr[n] = tot;
}

// atomic-free scatter, dst-partitioned into 8 groups (XCD swizzle: blockIdx&7)
__global__ __launch_bounds__(256) void scatter_part(const int* __restrict__ ei,
                                                    const int* __restrict__ rowptr,
                                                    const int* __restrict__ rank,
                                                    int* __restrict__ srcs, int E, int n) {
    int b = blockIdx.x;
    int part = b & 7;
    int base = (b >> 3) * SCAT_CH;
    int tot = E + n;
    int thr = (n + 7) >> 3;
    int lo = part * thr;
    int hi = lo + thr; if (hi > n) hi = n;
#pragma unroll
    for (int j = 0; j < SCAT_CH / 256; ++j) {
        int i = base + j * 256 + threadIdx.x;
        if (i >= tot) continue;
        int d = (i < E) ? ei[E + i] : (i - E);
        if (d < lo || d >= hi) continue;
        int s = (i < E) ? ei[i] : d;
        srcs[rowptr[d] + rank[i]] = s;
    }
}

// ---------------- conversions ----------------

// W [128 K][128 N] fp32 -> Bt [128 N][128 K] bf16 (transpose + round)
__global__ __launch_bounds__(256) void convWt_kernel(const float* __restrict__ W,
                                                     unsigned short* __restrict__ Bt) {
    int i = blockIdx.x * 256 + threadIdx.x;   // 16384
    int k = i >> 7, n = i & 127;
    Bt[n * 128 + k] = bf16bits(W[i]);
}

// ---------------- GEMM layer 1: Hb = split(x) @ B1, alpha1 fused ----------------

__global__ __launch_bounds__(256) void gemm1_fused(const float* __restrict__ x,
                                                   const unsigned short* __restrict__ Bt,
                                                   unsigned short* __restrict__ Hb,
                                                   const float* __restrict__ a_src,
                                                   const float* __restrict__ a_dst,
                                                   float* __restrict__ asrc,
                                                   float* __restrict__ adst, int M) {
    __shared__ unsigned short Bs[128 * LDS_STRIDE];
    int t = threadIdx.x;
    for (int i = t; i < 128 * 16; i += 256) {
        int r = i >> 4, c = (i & 15) * 8;
        uint4 v = *reinterpret_cast<const uint4*>(Bt + r * 128 + c);
        *reinterpret_cast<uint4*>(&Bs[r * LDS_STRIDE + c]) = v;
    }
    __syncthreads();

    int wave = t >> 6, lane = t & 63;
    int m16 = lane & 15, quad = lane >> 4;
    int row0 = blockIdx.x * 64 + wave * 16;
    int arow = row0 + m16;
    if (arow > M - 1) arow = M - 1;           // clamp loads; stores predicated

    f32x4 acc[8] = {};
#pragma unroll
    for (int ks = 0; ks < 4; ++ks) {
        int k0 = ks * 32 + quad * 8;
        float4 v0 = *reinterpret_cast<const float4*>(x + (size_t)arow * 128 + k0);
        float4 v1 = *reinterpret_cast<const float4*>(x + (size_t)arow * 128 + k0 + 4);
        float vv[8] = {v0.x, v0.y, v0.z, v0.w, v1.x, v1.y, v1.z, v1.w};
        union { unsigned short u[8]; bf16x8 v; } ahi, alo;
#pragma unroll
        for (int j = 0; j < 8; ++j) {
            ahi.u[j] = bf16bits(vv[j]);
            alo.u[j] = bf16bits(vv[j] - bf16back(vv[j]));
        }
#pragma unroll
        for (int nt = 0; nt < 8; ++nt) {
            bf16x8 b = __builtin_bit_cast(bf16x8,
                *reinterpret_cast<const uint4*>(&Bs[(nt * 16 + m16) * LDS_STRIDE + k0]));
            acc[nt] = __builtin_amdgcn_mfma_f32_16x16x32_bf16(alo.v, b, acc[nt], 0, 0, 0);
            acc[nt] = __builtin_amdgcn_mfma_f32_16x16x32_bf16(ahi.v, b, acc[nt], 0, 0, 0);
        }
    }
    // C/D layout: col = lane&15, row = quad*4 + reg   [m89-verified]
#pragma unroll
    for (int nt = 0; nt < 8; ++nt) {
#pragma unroll
        for (int r = 0; r < 4; ++r) {
            int gr = row0 + quad * 4 + r;
            if (gr < M) Hb[(size_t)gr * 128 + nt * 16 + m16] = bf16bits(acc[nt][r]);
        }
    }
    // fused alpha1: per (row, head) dot over 128 cols; lane holds cols nt*16+m16
    float asa[4], asb[4], ada[4], adb[4];
#pragma unroll
    for (int h = 0; h < 4; ++h) {
        asa[h] = a_src[h * 32 + m16];
        asb[h] = a_src[h * 32 + 16 + m16];
        ada[h] = a_dst[h * 32 + m16];
        adb[h] = a_dst[h * 32 + 16 + m16];
    }
#pragma unroll
    for (int r = 0; r < 4; ++r) {
        int gr = row0 + quad * 4 + r;
        float ps[4], pd[4];
#pragma unroll
        for (int h = 0; h < 4; ++h) {
            ps[h] = acc[2 * h][r] * asa[h] + acc[2 * h + 1][r] * asb[h];
            pd[h] = acc[2 * h][r] * ada[h] + acc[2 * h + 1][r] * adb[h];
        }
#pragma unroll
        for (int off = 1; off < 16; off <<= 1) {
#pragma unroll
            for (int h = 0; h < 4; ++h) {
                ps[h] += __shfl_xor(ps[h], off, 64);
                pd[h] += __shfl_xor(pd[h], off, 64);
            }
        }
        if (m16 == 0 && gr < M) {
#pragma unroll
            for (int h = 0; h < 4; ++h) {
                asrc[gr * 4 + h] = ps[h];
                adst[gr * 4 + h] = pd[h];
            }
        }
    }
}

// ---------------- GEMM layer 2: Hb = (Ahi+Alo) @ B2, alpha2 fused ----------------

__global__ __launch_bounds__(256) void gemm2_fused(const unsigned short* __restrict__ Ahi,
                                                   const unsigned short* __restrict__ Alo,
                                                   const unsigned short* __restrict__ Bt,
                                                   unsigned short* __restrict__ Hb,
                                                   const float* __restrict__ a_src,
                                                   const float* __restrict__ a_dst,
                                                   float* __restrict__ asrc,
                                                   float* __restrict__ adst, int M) {
    __shared__ unsigned short Bs[128 * LDS_STRIDE];
    int t = threadIdx.x;
    for (int i = t; i < 128 * 16; i += 256) {
        int r = i >> 4, c = (i & 15) * 8;
        uint4 v = *reinterpret_cast<const uint4*>(Bt + r * 128 + c);
        *reinterpret_cast<uint4*>(&Bs[r * LDS_STRIDE + c]) = v;
    }
    __syncthreads();

    int wave = t >> 6, lane = t & 63;
    int m16 = lane & 15, quad = lane >> 4;
    int row0 = blockIdx.x * 64 + wave * 16;
    int arow = row0 + m16;
    if (arow > M - 1) arow = M - 1;

    f32x4 acc[8] = {};
#pragma unroll
    for (int ks = 0; ks < 4; ++ks) {
        int k0 = ks * 32 + quad * 8;
        bf16x8 a_hi = __builtin_bit_cast(bf16x8,
            *reinterpret_cast<const uint4*>(Ahi + (size_t)arow * 128 + k0));
        bf16x8 a_lo = __builtin_bit_cast(bf16x8,
            *reinterpret_cast<const uint4*>(Alo + (size_t)arow * 128 + k0));
#pragma unroll
        for (int nt = 0; nt < 8; ++nt) {
            bf16x8 b = __builtin_bit_cast(bf16x8,
                *reinterpret_cast<const uint4*>(&Bs[(nt * 16 + m16) * LDS_STRIDE + k0]));
            acc[nt] = __builtin_amdgcn_mfma_f32_16x16x32_bf16(a_lo, b, acc[nt], 0, 0, 0);
            acc[nt] = __builtin_amdgcn_mfma_f32_16x16x32_bf16(a_hi, b, acc[nt], 0, 0, 0);
        }
    }
#pragma unroll
    for (int nt = 0; nt < 8; ++nt) {
#pragma unroll
        for (int r = 0; r < 4; ++r) {
            int gr = row0 + quad * 4 + r;
            if (gr < M) Hb[(size_t)gr * 128 + nt * 16 + m16] = bf16bits(acc[nt][r]);
        }
    }
    // fused alpha2: single head over 128 cols
    float as2[8], ad2[8];
#pragma unroll
    for (int nt = 0; nt < 8; ++nt) {
        as2[nt] = a_src[nt * 16 + m16];
        ad2[nt] = a_dst[nt * 16 + m16];
    }
#pragma unroll
    for (int r = 0; r < 4; ++r) {
        int gr = row0 + quad * 4 + r;
        float ps = 0.f, pd = 0.f;
#pragma unroll
        for (int nt = 0; nt < 8; ++nt) {
            ps += acc[nt][r] * as2[nt];
            pd += acc[nt][r] * ad2[nt];
        }
#pragma unroll
        for (int off = 1; off < 16; off <<= 1) {
            ps += __shfl_xor(ps, off, 64);
            pd += __shfl_xor(pd, off, 64);
        }
        if (m16 == 0 && gr < M) {
            asrc[gr] = ps;
            adst[gr] = pd;
        }
    }
}

// ---------------- aggregation ----------------
// Lane decomposition: m16 = lane&15 -> 8-channel group (16 B of the 256 B
// row); quad = lane>>4 -> edge slot. One dwordx4 gather covers 4 edges.
// Per-lane exp (no per-edge shfl); den/acc quad-reduced once per node.

// layer-1: 4 heads x 32 ch; head of channel-group = m16>>2.
// fused bias+ReLU; writes layer-2 input as bf16 hi/lo split.
__global__ __launch_bounds__(256) void agg1_kernel(const unsigned short* __restrict__ Hb,
                                                   const float* __restrict__ asrc,
                                                   const float* __restrict__ adst,
                                                   const int* __restrict__ rowptr,
                                                   const int* __restrict__ srcs,
                                                   const float* __restrict__ bias,
                                                   unsigned short* __restrict__ ohi,
                                                   unsigned short* __restrict__ olo, int n) {
    int wid = (blockIdx.x * 256 + threadIdx.x) >> 6;
    int lane = threadIdx.x & 63;
    if (wid >= n) return;
    int m16 = lane & 15, quad = lane >> 4;
    int hd = m16 >> 2;
    int d = wid;
    int beg = rowptr[d], end = rowptr[d + 1];
    float adh = adst[d * 4 + hd];
    const uint4* H4 = reinterpret_cast<const uint4*>(Hb);
    float acc[8] = {};
    float den = 0.f;

    auto body = [&](int p, bool chk) {
        int ep = p + quad;
        bool valid = !chk || (ep < end);
        int se = srcs[valid ? ep : beg];
        float e = asrc[se * 4 + hd] + adh;
        e = (e > 0.f) ? e : 0.2f * e;          // leaky_relu
        float pv = __expf(e);
        if (!valid) pv = 0.f;
        den += pv;
        uint4 hv = H4[(size_t)se * 16 + m16];
        float2 f0 = unpk(hv.x), f1 = unpk(hv.y), f2 = unpk(hv.z), f3 = unpk(hv.w);
        acc[0] += pv * f0.x; acc[1] += pv * f0.y;
        acc[2] += pv * f1.x; acc[3] += pv * f1.y;
        acc[4] += pv * f2.x; acc[5] += pv * f2.y;
        acc[6] += pv * f3.x; acc[7] += pv * f3.y;
    };
    int p = beg;
    for (; p + 8 <= end; p += 8) { body(p, false); body(p + 4, false); }
    for (; p < end; p += 4) body(p, true);

#pragma unroll
    for (int off = 16; off < 64; off <<= 1) {
        den += __shfl_xor(den, off, 64);
#pragma unroll
        for (int j = 0; j < 8; ++j) acc[j] += __shfl_xor(acc[j], off, 64);
    }
    float inv = 1.f / den;
    const float4* bv4 = reinterpret_cast<const float4*>(bias);
    float4 b0 = bv4[m16 * 2], b1 = bv4[m16 * 2 + 1];
    float v0 = fmaxf(b0.x + acc[0] * inv, 0.f);
    float v1 = fmaxf(b0.y + acc[1] * inv, 0.f);
    float v2 = fmaxf(b0.z + acc[2] * inv, 0.f);
    float v3 = fmaxf(b0.w + acc[3] * inv, 0.f);
    float v4 = fmaxf(b1.x + acc[4] * inv, 0.f);
    float v5 = fmaxf(b1.y + acc[5] * inv, 0.f);
    float v6 = fmaxf(b1.z + acc[6] * inv, 0.f);
    float v7 = fmaxf(b1.w + acc[7] * inv, 0.f);
    if (quad == 0) {
        uint4 hw;
        hw.x = pk2(v0, v1); hw.y = pk2(v2, v3); hw.z = pk2(v4, v5); hw.w = pk2(v6, v7);
        *reinterpret_cast<uint4*>(ohi + (size_t)d * 128 + m16 * 8) = hw;
    }
    if (quad == 1) {
        uint4 lw;
        lw.x = pk2(v0 - bf16back(v0), v1 - bf16back(v1));
        lw.y = pk2(v2 - bf16back(v2), v3 - bf16back(v3));
        lw.z = pk2(v4 - bf16back(v4), v5 - bf16back(v5));
        lw.w = pk2(v6 - bf16back(v6), v7 - bf16back(v7));
        *reinterpret_cast<uint4*>(olo + (size_t)d * 128 + m16 * 8) = lw;
    }
}

// layer-2: 1 head x 128 ch; + b2, no ReLU; fp32 output.
__global__ __launch_bounds__(256) void agg2_kernel(const unsigned short* __restrict__ Hb,
                                                   const float* __restrict__ asrc,
                                                   const float* __restrict__ adst,
                                                   const int* __restrict__ rowptr,
                                                   const int* __restrict__ srcs,
                                                   const float* __restrict__ bias,
                                                   float* __restrict__ out, int n) {
    int wid = (blockIdx.x * 256 + threadIdx.x) >> 6;
    int lane = threadIdx.x & 63;
    if (wid >= n) return;
    int m16 = lane & 15, quad = lane >> 4;
    int d = wid;
    int beg = rowptr[d], end = rowptr[d + 1];
    float ad = adst[d];
    const uint4* H4 = reinterpret_cast<const uint4*>(Hb);
    float acc[8] = {};
    float den = 0.f;

    auto body = [&](int p, bool chk) {
        int ep = p + quad;
        bool valid = !chk || (ep < end);
        int se = srcs[valid ? ep : beg];
        float e = asrc[se] + ad;
        e = (e > 0.f) ? e : 0.2f * e;
        float pv = __expf(e);
        if (!valid) pv = 0.f;
        den += pv;
        uint4 hv = H4[(size_t)se * 16 + m16];
        float2 f0 = unpk(hv.x), f1 = unpk(hv.y), f2 = unpk(hv.z), f3 = unpk(hv.w);
        acc[0] += pv * f0.x; acc[1] += pv * f0.y;
        acc[2] += pv * f1.x; acc[3] += pv * f1.y;
        acc[4] += pv * f2.x; acc[5] += pv * f2.y;
        acc[6] += pv * f3.x; acc[7] += pv * f3.y;
    };
    int p = beg;
    for (; p + 8 <= end; p += 8) { body(p, false); body(p + 4, false); }
    for (; p < end; p += 4) body(p, true);

#pragma unroll
    for (int off = 16; off < 64; off <<= 1) {
        den += __shfl_xor(den, off, 64);
#pragma unroll
        for (int j = 0; j < 8; ++j) acc[j] += __shfl_xor(acc[j], off, 64);
    }
    float inv = 1.f / den;
    const float4* bv4 = reinterpret_cast<const float4*>(bias);
    float4 b0 = bv4[m16 * 2], b1 = bv4[m16 * 2 + 1];
    if (quad == 0) {
        float4 o;
        o.x = b0.x + acc[0] * inv; o.y = b0.y + acc[1] * inv;
        o.z = b0.z + acc[2] * inv; o.w = b0.w + acc[3] * inv;
        *reinterpret_cast<float4*>(out + (size_t)d * 128 + m16 * 8) = o;
    }
    if (quad == 1) {
        float4 o;
        o.x = b1.x + acc[4] * inv; o.y = b1.y + acc[5] * inv;
        o.z = b1.z + acc[6] * inv; o.w = b1.w + acc[7] * inv;
        *reinterpret_cast<float4*>(out + (size_t)d * 128 + m16 * 8 + 4) = o;
    }
}

// ---------------- launch ----------------

extern "C" void kernel_launch(void* const* d_in, const int* in_sizes, int n_in,
                              void* d_out, int out_size, void* d_ws, size_t ws_size,
                              hipStream_t stream) {
    const float* x   = (const float*)d_in[0];
    const int*   ei  = (const int*)d_in[1];
    const float* W1  = (const float*)d_in[2];
    const float* as1 = (const float*)d_in[3];
    const float* ad1 = (const float*)d_in[4];
    const float* b1  = (const float*)d_in[5];
    const float* W2  = (const float*)d_in[6];
    const float* as2 = (const float*)d_in[7];
    const float* ad2 = (const float*)d_in[8];
    const float* b2  = (const float*)d_in[9];

    int N = in_sizes[0] / 128;
    int E = in_sizes[1] / 2;
    int tot = E + N;
    int nb = (N + 255) / 256;           // scan blocks (<=256 required; N=50k -> 196)
    int nscat = (tot + SCAT_CH - 1) / SCAT_CH;

    char* wsb = (char*)d_ws;
    size_t off = 0;
    auto alloc = [&](size_t bytes) {
        void* p = wsb + off;
        off += (bytes + 255) & ~(size_t)255;
        return p;
    };
    unsigned short* Ahi = (unsigned short*)alloc((size_t)N * 128 * 2); // out1_hi (agg1 -> gemm2)
    unsigned short* Alo = (unsigned short*)alloc((size_t)N * 128 * 2); // out1_lo
    unsigned short* Hb  = (unsigned short*)alloc((size_t)N * 128 * 2); // h bf16 (h1 then h2)
    unsigned short* Bt1 = (unsigned short*)alloc(128 * 128 * 2);
    unsigned short* Bt2 = (unsigned short*)alloc(128 * 128 * 2);
    int*   counts = (int*)alloc((size_t)N * 4);
    int*   rowptr = (int*)alloc((size_t)(N + 1) * 4);
    int*   srcs   = (int*)alloc((size_t)tot * 4);
    int*   rank   = (int*)alloc((size_t)tot * 4);
    int*   bsum   = (int*)alloc(256 * 4);
    float* asrc1  = (float*)alloc((size_t)N * 4 * 4);
    float* adst1  = (float*)alloc((size_t)N * 4 * 4);
    float* asrc2  = (float*)alloc((size_t)N * 4);
    float* adst2  = (float*)alloc((size_t)N * 4);
    (void)ws_size; (void)n_in; (void)out_size;

    // CSR by dst (shared by both layers)
    hipMemsetAsync(counts, 0, (size_t)N * 4, stream);
    hist_rank<<<(tot + 255) / 256, 256, 0, stream>>>(ei, counts, rank, E, N);
    scan_partial<<<nb, 256, 0, stream>>>(counts, bsum, N);
    scan_bsums<<<1, 256, 0, stream>>>(bsum, nb);
    scan_final<<<nb, 256, 0, stream>>>(counts, bsum, rowptr, N, tot);
    scatter_part<<<nscat * 8, 256, 0, stream>>>(ei, rowptr, rank, srcs, E, N);

    // weight conversions
    convWt_kernel<<<64, 256, 0, stream>>>(W1, Bt1);
    convWt_kernel<<<64, 256, 0, stream>>>(W2, Bt2);

    int gblocks = (N + 63) / 64;

    // layer 1 (x split fused into GEMM; alpha1 fused into epilogue)
    gemm1_fused<<<gblocks, 256, 0, stream>>>(x, Bt1, Hb, as1, ad1, asrc1, adst1, N);
    agg1_kernel<<<(N + 3) / 4, 256, 0, stream>>>(Hb, asrc1, adst1, rowptr, srcs, b1,
                                                 Ahi, Alo, N);

    // layer 2 (alpha2 fused into epilogue)
    gemm2_fused<<<gblocks, 256, 0, stream>>>(Ahi, Alo, Bt2, Hb, as2, ad2, asrc2, adst2, N);
    agg2_kernel<<<(N + 3) / 4, 256, 0, stream>>>(Hb, asrc2, adst2, rowptr, srcs, b2,
                                                 (float*)d_out, N);
}

// Round 8
// 251.441 us; speedup vs baseline: 3.1323x; 1.0204x over previous
//
#include <hip/hip_runtime.h>
#include <hip/hip_bf16.h>

// ---------------------------------------------------------------------------
// 2-layer GAT on MI355X (gfx950).
//   CSR-by-dst: hist+rank (one atomic pass) / 3-stage parallel scan /
//   atomic-free dst-partitioned scatter (8-way XCD swizzle).
//   gemm1: fp32 x -> in-register bf16 hi/lo split -> MFMA (2-term A-split);
//          epilogue writes Hb (bf16) AND alpha1 (fused att dot + quad-reduce).
//   agg1: softmax-aggregate -> bias+ReLU -> single bf16 out1 (layer-2 A).
//   gemm2: single-term bf16 A (precision budget: absmax headroom 4.5x);
//          epilogue fuses alpha2.
//   agg kernels: lane = (channel-group m16, edge-slot quad); one dwordx4
//   gather covers 4 edges; per-lane exp; quad-reduce once per node.
//   Softmax without segment-max (scale-invariant; exponents bounded ~|10|).
// ---------------------------------------------------------------------------

typedef __attribute__((ext_vector_type(8))) short bf16x8;
typedef __attribute__((ext_vector_type(4))) float f32x4;

#define LDS_STRIDE 136  // 128 + 8 pad (bf16): row stride 68 dwords -> 2-way max (free)
#define SCAT_CH 4096    // edges per scatter block (256 threads x 16)

__device__ inline unsigned short bf16bits(float v) {
    __hip_bfloat16 h = __float2bfloat16(v);
    return __builtin_bit_cast(unsigned short, h);
}
__device__ inline float bf16back(float v) {
    __hip_bfloat16 h = __float2bfloat16(v);
    return __bfloat162float(h);
}
// packed pair (lo 16 bits = elem0, hi = elem1) -> two fp32
__device__ inline float2 unpk(unsigned int u) {
    float2 r;
    r.x = __builtin_bit_cast(float, u << 16);
    r.y = __builtin_bit_cast(float, u & 0xffff0000u);
    return r;
}
__device__ inline unsigned int pk2(float a, float b) {
    return (unsigned int)bf16bits(a) | ((unsigned int)bf16bits(b) << 16);
}

// ---------------- CSR build ----------------

__global__ __launch_bounds__(256) void hist_rank(const int* __restrict__ ei,
                                                 int* __restrict__ counts,
                                                 int* __restrict__ rank, int E, int n) {
    int i = blockIdx.x * 256 + threadIdx.x;
    int tot = E + n;
    if (i >= tot) return;
    int d = (i < E) ? ei[E + i] : (i - E);   // self-loops appended at the end
    int r = atomicAdd(&counts[d], 1);
    rank[i] = r;
}

__global__ __launch_bounds__(256) void scan_partial(const int* __restrict__ counts,
                                                    int* __restrict__ bsum, int n) {
    int t = threadIdx.x;
    int i = blockIdx.x * 256 + t;
    int v = (i < n) ? counts[i] : 0;
    for (int off = 32; off; off >>= 1) v += __shfl_down(v, off, 64);
    __shared__ int ws[4];
    if ((t & 63) == 0) ws[t >> 6] = v;
    __syncthreads();
    if (t == 0) bsum[blockIdx.x] = ws[0] + ws[1] + ws[2] + ws[3];
}

__global__ __launch_bounds__(256) void scan_bsums(int* __restrict__ bsum, int nb) {
    int t = threadIdx.x;
    int lane = t & 63, w = t >> 6;
    int orig = (t < nb) ? bsum[t] : 0;
    int v = orig;
    for (int off = 1; off < 64; off <<= 1) {
        int u = __shfl_up(v, off, 64);
        if (lane >= off) v += u;
    }
    __shared__ int ws[4];
    if (lane == 63) ws[w] = v;
    __syncthreads();
    int woff = 0;
    for (int i = 0; i < w; ++i) woff += ws[i];
    if (t < nb) bsum[t] = woff + v - orig;   // exclusive
}

__global__ __launch_bounds__(256) void scan_final(const int* __restrict__ counts,
                                                  const int* __restrict__ bsum,
                                                  int* __restrict__ rowptr, int n, int tot) {
    int t = threadIdx.x;
    int i = blockIdx.x * 256 + t;
    int lane = t & 63, w = t >> 6;
    int orig = (i < n) ? counts[i] : 0;
    int v = orig;
    for (int off = 1; off < 64; off <<= 1) {
        int u = __shfl_up(v, off, 64);
        if (lane >= off) v += u;
    }
    __shared__ int ws[4];
    if (lane == 63) ws[w] = v;
    __syncthreads();
    int woff = 0;
    for (int k = 0; k < w; ++k) woff += ws[k];
    int excl = bsum[blockIdx.x] + woff + v - orig;
    if (i < n) rowptr[i] = excl;
    if (blockIdx.x == 0 && t == 0) rowptr[n] = tot;
}

// atomic-free scatter, dst-partitioned into 8 groups (XCD swizzle: blockIdx&7)
__global__ __launch_bounds__(256) void scatter_part(const int* __restrict__ ei,
                                                    const int* __restrict__ rowptr,
                                                    const int* __restrict__ rank,
                                                    int* __restrict__ srcs, int E, int n) {
    int b = blockIdx.x;
    int part = b & 7;
    int base = (b >> 3) * SCAT_CH;
    int tot = E + n;
    int thr = (n + 7) >> 3;
    int lo = part * thr;
    int hi = lo + thr; if (hi > n) hi = n;
#pragma unroll
    for (int j = 0; j < SCAT_CH / 256; ++j) {
        int i = base + j * 256 + threadIdx.x;
        if (i >= tot) continue;
        int d = (i < E) ? ei[E + i] : (i - E);
        if (d < lo || d >= hi) continue;
        int s = (i < E) ? ei[i] : d;
        srcs[rowptr[d] + rank[i]] = s;
    }
}

// ---------------- conversions ----------------

// both weights: W [128 K][128 N] fp32 -> Bt [128 N][128 K] bf16 (transpose+round)
__global__ __launch_bounds__(256) void convWt2_kernel(const float* __restrict__ W1,
                                                      const float* __restrict__ W2,
                                                      unsigned short* __restrict__ Bt1,
                                                      unsigned short* __restrict__ Bt2) {
    int i = blockIdx.x * 256 + threadIdx.x;   // 32768
    const float* W = (i < 16384) ? W1 : W2;
    unsigned short* Bt = (i < 16384) ? Bt1 : Bt2;
    int j = i & 16383;
    int k = j >> 7, n = j & 127;
    Bt[n * 128 + k] = bf16bits(W[j]);
}

// ---------------- GEMM layer 1: Hb = split(x) @ B1, alpha1 fused ----------------

__global__ __launch_bounds__(256) void gemm1_fused(const float* __restrict__ x,
                                                   const unsigned short* __restrict__ Bt,
                                                   unsigned short* __restrict__ Hb,
                                                   const float* __restrict__ a_src,
                                                   const float* __restrict__ a_dst,
                                                   float* __restrict__ asrc,
                                                   float* __restrict__ adst, int M) {
    __shared__ unsigned short Bs[128 * LDS_STRIDE];
    int t = threadIdx.x;
    for (int i = t; i < 128 * 16; i += 256) {
        int r = i >> 4, c = (i & 15) * 8;
        uint4 v = *reinterpret_cast<const uint4*>(Bt + r * 128 + c);
        *reinterpret_cast<uint4*>(&Bs[r * LDS_STRIDE + c]) = v;
    }
    __syncthreads();

    int wave = t >> 6, lane = t & 63;
    int m16 = lane & 15, quad = lane >> 4;
    int row0 = blockIdx.x * 64 + wave * 16;
    int arow = row0 + m16;
    if (arow > M - 1) arow = M - 1;           // clamp loads; stores predicated

    f32x4 acc[8] = {};
#pragma unroll
    for (int ks = 0; ks < 4; ++ks) {
        int k0 = ks * 32 + quad * 8;
        float4 v0 = *reinterpret_cast<const float4*>(x + (size_t)arow * 128 + k0);
        float4 v1 = *reinterpret_cast<const float4*>(x + (size_t)arow * 128 + k0 + 4);
        float vv[8] = {v0.x, v0.y, v0.z, v0.w, v1.x, v1.y, v1.z, v1.w};
        union { unsigned short u[8]; bf16x8 v; } ahi, alo;
#pragma unroll
        for (int j = 0; j < 8; ++j) {
            ahi.u[j] = bf16bits(vv[j]);
            alo.u[j] = bf16bits(vv[j] - bf16back(vv[j]));
        }
#pragma unroll
        for (int nt = 0; nt < 8; ++nt) {
            bf16x8 b = __builtin_bit_cast(bf16x8,
                *reinterpret_cast<const uint4*>(&Bs[(nt * 16 + m16) * LDS_STRIDE + k0]));
            acc[nt] = __builtin_amdgcn_mfma_f32_16x16x32_bf16(alo.v, b, acc[nt], 0, 0, 0);
            acc[nt] = __builtin_amdgcn_mfma_f32_16x16x32_bf16(ahi.v, b, acc[nt], 0, 0, 0);
        }
    }
    // C/D layout: col = lane&15, row = quad*4 + reg   [m89-verified]
#pragma unroll
    for (int nt = 0; nt < 8; ++nt) {
#pragma unroll
        for (int r = 0; r < 4; ++r) {
            int gr = row0 + quad * 4 + r;
            if (gr < M) Hb[(size_t)gr * 128 + nt * 16 + m16] = bf16bits(acc[nt][r]);
        }
    }
    // fused alpha1: per (row, head) dot over 128 cols; lane holds cols nt*16+m16
    float asa[4], asb[4], ada[4], adb[4];
#pragma unroll
    for (int h = 0; h < 4; ++h) {
        asa[h] = a_src[h * 32 + m16];
        asb[h] = a_src[h * 32 + 16 + m16];
        ada[h] = a_dst[h * 32 + m16];
        adb[h] = a_dst[h * 32 + 16 + m16];
    }
#pragma unroll
    for (int r = 0; r < 4; ++r) {
        int gr = row0 + quad * 4 + r;
        float ps[4], pd[4];
#pragma unroll
        for (int h = 0; h < 4; ++h) {
            ps[h] = acc[2 * h][r] * asa[h] + acc[2 * h + 1][r] * asb[h];
            pd[h] = acc[2 * h][r] * ada[h] + acc[2 * h + 1][r] * adb[h];
        }
#pragma unroll
        for (int off = 1; off < 16; off <<= 1) {
#pragma unroll
            for (int h = 0; h < 4; ++h) {
                ps[h] += __shfl_xor(ps[h], off, 64);
                pd[h] += __shfl_xor(pd[h], off, 64);
            }
        }
        if (m16 == 0 && gr < M) {
#pragma unroll
            for (int h = 0; h < 4; ++h) {
                asrc[gr * 4 + h] = ps[h];
                adst[gr * 4 + h] = pd[h];
            }
        }
    }
}

// ---------------- GEMM layer 2: Hb = A1 @ B2 (single-term bf16), alpha2 fused ----

__global__ __launch_bounds__(256) void gemm2_fused(const unsigned short* __restrict__ A1,
                                                   const unsigned short* __restrict__ Bt,
                                                   unsigned short* __restrict__ Hb,
                                                   const float* __restrict__ a_src,
                                                   const float* __restrict__ a_dst,
                                                   float* __restrict__ asrc,
                                                   float* __restrict__ adst, int M) {
    __shared__ unsigned short Bs[128 * LDS_STRIDE];
    int t = threadIdx.x;
    for (int i = t; i < 128 * 16; i += 256) {
        int r = i >> 4, c = (i & 15) * 8;
        uint4 v = *reinterpret_cast<const uint4*>(Bt + r * 128 + c);
        *reinterpret_cast<uint4*>(&Bs[r * LDS_STRIDE + c]) = v;
    }
    __syncthreads();

    int wave = t >> 6, lane = t & 63;
    int m16 = lane & 15, quad = lane >> 4;
    int row0 = blockIdx.x * 64 + wave * 16;
    int arow = row0 + m16;
    if (arow > M - 1) arow = M - 1;

    f32x4 acc[8] = {};
#pragma unroll
    for (int ks = 0; ks < 4; ++ks) {
        int k0 = ks * 32 + quad * 8;
        bf16x8 a = __builtin_bit_cast(bf16x8,
            *reinterpret_cast<const uint4*>(A1 + (size_t)arow * 128 + k0));
#pragma unroll
        for (int nt = 0; nt < 8; ++nt) {
            bf16x8 b = __builtin_bit_cast(bf16x8,
                *reinterpret_cast<const uint4*>(&Bs[(nt * 16 + m16) * LDS_STRIDE + k0]));
            acc[nt] = __builtin_amdgcn_mfma_f32_16x16x32_bf16(a, b, acc[nt], 0, 0, 0);
        }
    }
#pragma unroll
    for (int nt = 0; nt < 8; ++nt) {
#pragma unroll
        for (int r = 0; r < 4; ++r) {
            int gr = row0 + quad * 4 + r;
            if (gr < M) Hb[(size_t)gr * 128 + nt * 16 + m16] = bf16bits(acc[nt][r]);
        }
    }
    // fused alpha2: single head over 128 cols
    float as2[8], ad2[8];
#pragma unroll
    for (int nt = 0; nt < 8; ++nt) {
        as2[nt] = a_src[nt * 16 + m16];
        ad2[nt] = a_dst[nt * 16 + m16];
    }
#pragma unroll
    for (int r = 0; r < 4; ++r) {
        int gr = row0 + quad * 4 + r;
        float ps = 0.f, pd = 0.f;
#pragma unroll
        for (int nt = 0; nt < 8; ++nt) {
            ps += acc[nt][r] * as2[nt];
            pd += acc[nt][r] * ad2[nt];
        }
#pragma unroll
        for (int off = 1; off < 16; off <<= 1) {
            ps += __shfl_xor(ps, off, 64);
            pd += __shfl_xor(pd, off, 64);
        }
        if (m16 == 0 && gr < M) {
            asrc[gr] = ps;
            adst[gr] = pd;
        }
    }
}

// ---------------- aggregation ----------------
// Lane decomposition: m16 = lane&15 -> 8-channel group (16 B of the 256 B
// row); quad = lane>>4 -> edge slot. One dwordx4 gather covers 4 edges.
// Per-lane exp (no per-edge shfl); den/acc quad-reduced once per node.

// layer-1: 4 heads x 32 ch; head of channel-group = m16>>2.
// fused bias+ReLU; writes layer-2 input as single bf16 (precision budget).
__global__ __launch_bounds__(256) void agg1_kernel(const unsigned short* __restrict__ Hb,
                                                   const float* __restrict__ asrc,
                                                   const float* __restrict__ adst,
                                                   const int* __restrict__ rowptr,
                                                   const int* __restrict__ srcs,
                                                   const float* __restrict__ bias,
                                                   unsigned short* __restrict__ o1, int n) {
    int wid = (blockIdx.x * 256 + threadIdx.x) >> 6;
    int lane = threadIdx.x & 63;
    if (wid >= n) return;
    int m16 = lane & 15, quad = lane >> 4;
    int hd = m16 >> 2;
    int d = wid;
    int beg = rowptr[d], end = rowptr[d + 1];
    float adh = adst[d * 4 + hd];
    const uint4* H4 = reinterpret_cast<const uint4*>(Hb);
    float acc[8] = {};
    float den = 0.f;

    auto body = [&](int p, bool chk) {
        int ep = p + quad;
        bool valid = !chk || (ep < end);
        int se = srcs[valid ? ep : beg];
        float e = asrc[se * 4 + hd] + adh;
        e = (e > 0.f) ? e : 0.2f * e;          // leaky_relu
        float pv = __expf(e);
        if (!valid) pv = 0.f;
        den += pv;
        uint4 hv = H4[(size_t)se * 16 + m16];
        float2 f0 = unpk(hv.x), f1 = unpk(hv.y), f2 = unpk(hv.z), f3 = unpk(hv.w);
        acc[0] += pv * f0.x; acc[1] += pv * f0.y;
        acc[2] += pv * f1.x; acc[3] += pv * f1.y;
        acc[4] += pv * f2.x; acc[5] += pv * f2.y;
        acc[6] += pv * f3.x; acc[7] += pv * f3.y;
    };
    int p = beg;
    for (; p + 8 <= end; p += 8) { body(p, false); body(p + 4, false); }
    for (; p < end; p += 4) body(p, true);

#pragma unroll
    for (int off = 16; off < 64; off <<= 1) {
        den += __shfl_xor(den, off, 64);
#pragma unroll
        for (int j = 0; j < 8; ++j) acc[j] += __shfl_xor(acc[j], off, 64);
    }
    if (quad == 0) {
        float inv = 1.f / den;
        const float4* bv4 = reinterpret_cast<const float4*>(bias);
        float4 b0 = bv4[m16 * 2], b1 = bv4[m16 * 2 + 1];
        uint4 hw;
        hw.x = pk2(fmaxf(b0.x + acc[0] * inv, 0.f), fmaxf(b0.y + acc[1] * inv, 0.f));
        hw.y = pk2(fmaxf(b0.z + acc[2] * inv, 0.f), fmaxf(b0.w + acc[3] * inv, 0.f));
        hw.z = pk2(fmaxf(b1.x + acc[4] * inv, 0.f), fmaxf(b1.y + acc[5] * inv, 0.f));
        hw.w = pk2(fmaxf(b1.z + acc[6] * inv, 0.f), fmaxf(b1.w + acc[7] * inv, 0.f));
        *reinterpret_cast<uint4*>(o1 + (size_t)d * 128 + m16 * 8) = hw;
    }
}

// layer-2: 1 head x 128 ch; + b2, no ReLU; fp32 output.
__global__ __launch_bounds__(256) void agg2_kernel(const unsigned short* __restrict__ Hb,
                                                   const float* __restrict__ asrc,
                                                   const float* __restrict__ adst,
                                                   const int* __restrict__ rowptr,
                                                   const int* __restrict__ srcs,
                                                   const float* __restrict__ bias,
                                                   float* __restrict__ out, int n) {
    int wid = (blockIdx.x * 256 + threadIdx.x) >> 6;
    int lane = threadIdx.x & 63;
    if (wid >= n) return;
    int m16 = lane & 15, quad = lane >> 4;
    int d = wid;
    int beg = rowptr[d], end = rowptr[d + 1];
    float ad = adst[d];
    const uint4* H4 = reinterpret_cast<const uint4*>(Hb);
    float acc[8] = {};
    float den = 0.f;

    auto body = [&](int p, bool chk) {
        int ep = p + quad;
        bool valid = !chk || (ep < end);
        int se = srcs[valid ? ep : beg];
        float e = asrc[se] + ad;
        e = (e > 0.f) ? e : 0.2f * e;
        float pv = __expf(e);
        if (!valid) pv = 0.f;
        den += pv;
        uint4 hv = H4[(size_t)se * 16 + m16];
        float2 f0 = unpk(hv.x), f1 = unpk(hv.y), f2 = unpk(hv.z), f3 = unpk(hv.w);
        acc[0] += pv * f0.x; acc[1] += pv * f0.y;
        acc[2] += pv * f1.x; acc[3] += pv * f1.y;
        acc[4] += pv * f2.x; acc[5] += pv * f2.y;
        acc[6] += pv * f3.x; acc[7] += pv * f3.y;
    };
    int p = beg;
    for (; p + 8 <= end; p += 8) { body(p, false); body(p + 4, false); }
    for (; p < end; p += 4) body(p, true);

#pragma unroll
    for (int off = 16; off < 64; off <<= 1) {
        den += __shfl_xor(den, off, 64);
#pragma unroll
        for (int j = 0; j < 8; ++j) acc[j] += __shfl_xor(acc[j], off, 64);
    }
    float inv = 1.f / den;
    const float4* bv4 = reinterpret_cast<const float4*>(bias);
    float4 b0 = bv4[m16 * 2], b1 = bv4[m16 * 2 + 1];
    if (quad == 0) {
        float4 o;
        o.x = b0.x + acc[0] * inv; o.y = b0.y + acc[1] * inv;
        o.z = b0.z + acc[2] * inv; o.w = b0.w + acc[3] * inv;
        *reinterpret_cast<float4*>(out + (size_t)d * 128 + m16 * 8) = o;
    }
    if (quad == 1) {
        float4 o;
        o.x = b1.x + acc[4] * inv; o.y = b1.y + acc[5] * inv;
        o.z = b1.z + acc[6] * inv; o.w = b1.w + acc[7] * inv;
        *reinterpret_cast<float4*>(out + (size_t)d * 128 + m16 * 8 + 4) = o;
    }
}

// ---------------- launch ----------------

extern "C" void kernel_launch(void* const* d_in, const int* in_sizes, int n_in,
                              void* d_out, int out_size, void* d_ws, size_t ws_size,
                              hipStream_t stream) {
    const float* x   = (const float*)d_in[0];
    const int*   ei  = (const int*)d_in[1];
    const float* W1  = (const float*)d_in[2];
    const float* as1 = (const float*)d_in[3];
    const float* ad1 = (const float*)d_in[4];
    const float* b1  = (const float*)d_in[5];
    const float* W2  = (const float*)d_in[6];
    const float* as2 = (const float*)d_in[7];
    const float* ad2 = (const float*)d_in[8];
    const float* b2  = (const float*)d_in[9];

    int N = in_sizes[0] / 128;
    int E = in_sizes[1] / 2;
    int tot = E + N;
    int nb = (N + 255) / 256;           // scan blocks (<=256 required; N=50k -> 196)
    int nscat = (tot + SCAT_CH - 1) / SCAT_CH;

    char* wsb = (char*)d_ws;
    size_t off = 0;
    auto alloc = [&](size_t bytes) {
        void* p = wsb + off;
        off += (bytes + 255) & ~(size_t)255;
        return p;
    };
    unsigned short* A1  = (unsigned short*)alloc((size_t)N * 128 * 2); // out1 bf16 (agg1->gemm2)
    unsigned short* Hb  = (unsigned short*)alloc((size_t)N * 128 * 2); // h bf16 (h1 then h2)
    unsigned short* Bt1 = (unsigned short*)alloc(128 * 128 * 2);
    unsigned short* Bt2 = (unsigned short*)alloc(128 * 128 * 2);
    int*   counts = (int*)alloc((size_t)N * 4);
    int*   rowptr = (int*)alloc((size_t)(N + 1) * 4);
    int*   srcs   = (int*)alloc((size_t)tot * 4);
    int*   rank   = (int*)alloc((size_t)tot * 4);
    int*   bsum   = (int*)alloc(256 * 4);
    float* asrc1  = (float*)alloc((size_t)N * 4 * 4);
    float* adst1  = (float*)alloc((size_t)N * 4 * 4);
    float* asrc2  = (float*)alloc((size_t)N * 4);
    float* adst2  = (float*)alloc((size_t)N * 4);
    (void)ws_size; (void)n_in; (void)out_size;

    // CSR by dst (shared by both layers)
    hipMemsetAsync(counts, 0, (size_t)N * 4, stream);
    hist_rank<<<(tot + 255) / 256, 256, 0, stream>>>(ei, counts, rank, E, N);
    scan_partial<<<nb, 256, 0, stream>>>(counts, bsum, N);
    scan_bsums<<<1, 256, 0, stream>>>(bsum, nb);
    scan_final<<<nb, 256, 0, stream>>>(counts, bsum, rowptr, N, tot);
    scatter_part<<<nscat * 8, 256, 0, stream>>>(ei, rowptr, rank, srcs, E, N);

    // weight conversions (both in one launch)
    convWt2_kernel<<<128, 256, 0, stream>>>(W1, W2, Bt1, Bt2);

    int gblocks = (N + 63) / 64;

    // layer 1 (x split fused into GEMM; alpha1 fused into epilogue)
    gemm1_fused<<<gblocks, 256, 0, stream>>>(x, Bt1, Hb, as1, ad1, asrc1, adst1, N);
    agg1_kernel<<<(N + 3) / 4, 256, 0, stream>>>(Hb, asrc1, adst1, rowptr, srcs, b1, A1, N);

    // layer 2 (single-term bf16 A; alpha2 fused into epilogue)
    gemm2_fused<<<gblocks, 256, 0, stream>>>(A1, Bt2, Hb, as2, ad2, asrc2, adst2, N);
    agg2_kernel<<<(N + 3) / 4, 256, 0, stream>>>(Hb, asrc2, adst2, rowptr, srcs, b2,
                                                 (float*)d_out, N);
}